// Round 1
// 410.029 us; speedup vs baseline: 1.0217x; 1.0217x over previous
//
#include <hip/hip_runtime.h>
#include <hip/hip_bf16.h>
#include <stdint.h>

// ---------------------------------------------------------------------------
// MultiHeadAttention on MI355X (gfx950).
// b=2, n=1024, DIM=1024, H=16, dh=64.  Outputs: out (2M f32) ++ attn (33.5M f32).
// GEMMs: bf16 MFMA 16x16x32, hi/lo split (3 MFMAs) => ~fp32 accuracy.
// R3: fused logits+softmax -> normalized u16 P (no raw-logit round trip);
//     attn written by a register-transpose dequant kernel (no LDS);
//     K4 scale = 1/65535 constant.
// R4: k_logits_softmax 256->512 threads (8 waves, 2 waves/SIMD).  The kernel
//     is latency-bound at 1 block/CU (134 KiB LDS): Occupancy was 11%,
//     MfmaUtil 4.8%, VALUBusy 17%, HBM 12.7% -- nothing busy.  Doubling
//     resident waves per SIMD hides DMA/LDS/sync latency.
// ---------------------------------------------------------------------------

#define NB   2
#define SEQ  1024
#define CDIM 1024
#define NH   16
#define HD   64
#define ROWS (NB*SEQ)          // 2048
#define ATT_SCALE 0.125f       // 64^-0.5
#define S23  1028              // slab row stride (dwords), == 4 mod 32

typedef __attribute__((ext_vector_type(8))) short bf16x8;
typedef __attribute__((ext_vector_type(4))) float f32x4;

#define MFMA16(a,b,c) __builtin_amdgcn_mfma_f32_16x16x32_bf16((a),(b),(c),0,0,0)

static __device__ __forceinline__ unsigned short f2bf(float f) {
  uint32_t x = __builtin_bit_cast(uint32_t, f);
  return (unsigned short)((x + 0x7fffu + ((x >> 16) & 1u)) >> 16);   // RTN-even
}
static __device__ __forceinline__ float bf2f(unsigned short u) {
  uint32_t x = ((uint32_t)u) << 16;
  return __builtin_bit_cast(float, x);
}

// async global->LDS DMA, 16B/lane; lds dest = wave-uniform base + lane*16
static __device__ __forceinline__ void gl_lds16(const unsigned short* g,
                                                unsigned short* l) {
  __builtin_amdgcn_global_load_lds(
      (const __attribute__((address_space(1))) unsigned int*)g,
      (__attribute__((address_space(3))) unsigned int*)l,
      16, 0, 0);
}

// ---------------------------------------------------------------------------
// K0: fp32 -> bf16 hi/lo split for x and concatenated W = [Wq; Wkv; Wp]
// ---------------------------------------------------------------------------
__global__ __launch_bounds__(256) void k_convert(
    const float* __restrict__ x, const float* __restrict__ Wq,
    const float* __restrict__ Wkv, const float* __restrict__ Wp,
    unsigned short* __restrict__ Xhi, unsigned short* __restrict__ Xlo,
    unsigned short* __restrict__ Whi, unsigned short* __restrict__ Wlo)
{
  const int NX = ROWS * CDIM;
  const int NW = 4096 * CDIM;
  int i = blockIdx.x * 256 + threadIdx.x;
  if (i < NX) {
    float f = x[i];
    unsigned short h = f2bf(f);
    Xhi[i] = h; Xlo[i] = f2bf(f - bf2f(h));
  } else if (i < NX + NW) {
    int w = i - NX;
    int j = w >> 10, c = w & 1023;
    float f = (j < 1024) ? Wq[(size_t)j*1024 + c]
            : (j < 3072) ? Wkv[(size_t)(j-1024)*1024 + c]
                         : Wp[(size_t)(j-3072)*1024 + c];
    unsigned short h = f2bf(f);
    Whi[w] = h; Wlo[w] = f2bf(f - bf2f(h));
  }
}

// ---------------------------------------------------------------------------
// Templated NT-GEMM core (split bf16, BK=32, 256 threads = 2x2 waves)
// ---------------------------------------------------------------------------
struct EpiQKV {
  const float* bq; const float* bkv;
  unsigned short *Qhi, *Qlo, *Khi, *Klo, *Vthi, *Vtlo;
  __device__ __forceinline__ void operator()(int m, int n, float v) const {
    if (n < 1024) {                       // Q
      v += bq[n];
      unsigned short h = f2bf(v);
      size_t o = (size_t)m*1024 + n;
      Qhi[o] = h; Qlo[o] = f2bf(v - bf2f(h));
    } else if (n < 2048) {                // K
      v += bkv[n - 1024];
      size_t o = (size_t)m*1024 + (n - 1024);
      unsigned short h = f2bf(v);
      Khi[o] = h; Klo[o] = f2bf(v - bf2f(h));
    } else {                              // V -> transposed [b][h][d][m]
      v += bkv[n - 1024];
      int c = n - 2048;
      int hh = c >> 6, d = c & 63;
      int b = m >> 10, mm = m & 1023;
      size_t o = ((size_t)((b*NH + hh)*HD + d))*SEQ + mm;
      unsigned short h = f2bf(v);
      Vthi[o] = h; Vtlo[o] = f2bf(v - bf2f(h));
    }
  }
};
struct EpiOut {
  const float* bp; float* out;
  __device__ __forceinline__ void operator()(int m, int n, float v) const {
    out[(size_t)m*1024 + n] = v + bp[n];
  }
};

template <int BM, int BN, class Epi>
__device__ __forceinline__ void gemm_core(
    const unsigned short* __restrict__ Ahi, const unsigned short* __restrict__ Alo, int lda,
    const unsigned short* __restrict__ Bhi, const unsigned short* __restrict__ Blo, int ldb,
    int K, const Epi& epi)
{
  constexpr int FM = BM/32, FN = BN/32;
  constexpr int CA = BM/16, CB = BN/16;
  constexpr int TOT = 2*(CA+CB);
  __shared__ unsigned short sAh[BM*32], sAl[BM*32], sBh[BN*32], sBl[BN*32];
  const int tid  = threadIdx.x;
  const int lane = tid & 63, wave = tid >> 6;
  const int wm = wave & 1, wn = wave >> 1;
  const int bn = blockIdx.x * BN, bm = blockIdx.y * BM;
  const int r = lane & 15, q = lane >> 4;
  const int crow = lane >> 2, ccol = (lane & 3) * 8;

  f32x4 acc[FM][FN];
  #pragma unroll
  for (int i = 0; i < FM; i++)
    #pragma unroll
    for (int j = 0; j < FN; j++) {
      acc[i][j][0]=0.f; acc[i][j][1]=0.f; acc[i][j][2]=0.f; acc[i][j][3]=0.f;
    }

  for (int k0 = 0; k0 < K; k0 += 32) {
    #pragma unroll
    for (int t = 0; t < TOT/4; t++) {
      int c = wave + t*4;
      const unsigned short* gb; unsigned short* sb; int rr, grow, ld;
      if (c < CA)            { gb=Ahi; sb=sAh; rr=c;         grow=bm; ld=lda; }
      else if (c < 2*CA)     { gb=Alo; sb=sAl; rr=c-CA;      grow=bm; ld=lda; }
      else if (c < 2*CA+CB)  { gb=Bhi; sb=sBh; rr=c-2*CA;    grow=bn; ld=ldb; }
      else                   { gb=Blo; sb=sBl; rr=c-2*CA-CB; grow=bn; ld=ldb; }
      int row = rr*16 + crow;
      gl_lds16(gb + (size_t)(grow + row)*ld + k0 + ccol, sb + rr*512);
    }
    __syncthreads();
    bf16x8 ah[FM], al[FM], bh[FN], bl[FN];
    #pragma unroll
    for (int i = 0; i < FM; i++) {
      int oa = (wm*(BM/2) + i*16 + r)*32 + q*8;
      ah[i] = *(const bf16x8*)(sAh + oa);
      al[i] = *(const bf16x8*)(sAl + oa);
    }
    #pragma unroll
    for (int j = 0; j < FN; j++) {
      int ob = (wn*(BN/2) + j*16 + r)*32 + q*8;
      bh[j] = *(const bf16x8*)(sBh + ob);
      bl[j] = *(const bf16x8*)(sBl + ob);
    }
    #pragma unroll
    for (int i = 0; i < FM; i++)
      #pragma unroll
      for (int j = 0; j < FN; j++) {
        acc[i][j] = MFMA16(ah[i], bh[j], acc[i][j]);
        acc[i][j] = MFMA16(ah[i], bl[j], acc[i][j]);
        acc[i][j] = MFMA16(al[i], bh[j], acc[i][j]);
      }
    __syncthreads();
  }
  #pragma unroll
  for (int i = 0; i < FM; i++)
    #pragma unroll
    for (int j = 0; j < FN; j++)
      #pragma unroll
      for (int t = 0; t < 4; t++)
        epi(bm + wm*(BM/2) + i*16 + q*4 + t, bn + wn*(BN/2) + j*16 + r, acc[i][j][t]);
}

__global__ __launch_bounds__(256) void k_gemm_qkv(
    const unsigned short* Xhi, const unsigned short* Xlo,
    const unsigned short* Whi, const unsigned short* Wlo,
    const float* bq, const float* bkv,
    unsigned short* Qhi, unsigned short* Qlo,
    unsigned short* Khi, unsigned short* Klo,
    unsigned short* Vthi, unsigned short* Vtlo)
{
  EpiQKV e{bq, bkv, Qhi, Qlo, Khi, Klo, Vthi, Vtlo};
  gemm_core<128,128>(Xhi, Xlo, CDIM, Whi, Wlo, CDIM, CDIM, e);
}

__global__ __launch_bounds__(256) void k_gemm_out(
    const unsigned short* OAhi, const unsigned short* OAlo,
    const unsigned short* Wphi, const unsigned short* Wplo,
    const float* bp, float* out)
{
  EpiOut e{bp, out};
  gemm_core<64,64>(OAhi, OAlo, CDIM, Wphi, Wplo, CDIM, CDIM, e);
}

// ---------------------------------------------------------------------------
// K23: fused logits + softmax -> normalized u16 P in [b][h][n][m].
// Block = (16 n-rows, 8 heads, b); 512 thr (8 waves, 2 waves/SIMD).
// K streamed in 128-m DMA chunks (double-buffered, XOR-swizzled LDS).
// Slab [16n][S23] f32.
// ---------------------------------------------------------------------------
static __device__ __forceinline__ void stage_q23(
    const unsigned short* Qhi, const unsigned short* Qlo,
    size_t qrow0, int col0, unsigned short* sQ,
    int wave, int drow, int dseg)
{
  if (wave < 4) {
    int p = wave >> 1, t = wave & 1;
    const unsigned short* g = p ? Qlo : Qhi;
    gl_lds16(g + (qrow0 + t*8 + drow)*CDIM + col0 + dseg*8,
             sQ + p*1024 + t*512);
  }
}
static __device__ __forceinline__ void stage_k23(
    const unsigned short* Khi, const unsigned short* Klo,
    size_t krow0, int col0, unsigned short* dstbuf,
    int wave, int drow, int dseg)
{
  #pragma unroll
  for (int u = 0; u < 4; u++) {
    int c = wave*4 + u;
    int p = c >> 4, t = c & 15;
    const unsigned short* g = p ? Klo : Khi;
    gl_lds16(g + (krow0 + t*8 + drow)*CDIM + col0 + dseg*8,
             dstbuf + p*8192 + t*512);
  }
}

__global__ __launch_bounds__(512) void k_logits_softmax(
    const unsigned short* __restrict__ Qhi, const unsigned short* __restrict__ Qlo,
    const unsigned short* __restrict__ Khi, const unsigned short* __restrict__ Klo,
    unsigned short* __restrict__ P)
{
  const int nt = blockIdx.x, hg = blockIdx.y, b = blockIdx.z;
  const int n0 = nt*16;
  __shared__ unsigned short sQ[2*1024];       // [plane][16n x 64k] swizzled
  __shared__ unsigned short sK[2][2*8192];    // [buf][plane][128m x 64k] swizzled
  __shared__ float slab[16*S23];
  __shared__ float red[512];
  __shared__ float gmax[16], gscale[16];
  const int tid = threadIdx.x, lane = tid & 63, wave = tid >> 6;
  const int r = lane & 15, q = lane >> 4;
  const int drow = lane >> 3, dseg = (lane & 7) ^ drow;   // DMA swizzle
  const int sw = r & 7;                                   // read swizzle
  const size_t qrow0 = (size_t)b*SEQ + n0;
  const size_t krow0 = (size_t)b*SEQ;

  {   // initial stage: first head's Q + K chunk 0
    int col0 = (hg*8)*HD;
    stage_q23(Qhi, Qlo, qrow0, col0, sQ, wave, drow, dseg);
    stage_k23(Khi, Klo, krow0, col0, sK[0], wave, drow, dseg);
  }

  for (int hh = 0; hh < 8; hh++) {
    const int h = hg*8 + hh;
    const int col0 = h*HD;
    __syncthreads();          // staged Q/K0 arrived; slab free from prev head
    bf16x8 qh[2], ql[2];
    #pragma unroll
    for (int ks = 0; ks < 2; ks++) {
      int phys = r*64 + (((ks*4 + q) ^ sw))*8;
      qh[ks] = *(const bf16x8*)(sQ + phys);
      ql[ks] = *(const bf16x8*)(sQ + 1024 + phys);
    }
    for (int c128 = 0; c128 < 8; c128++) {
      unsigned short* cur = sK[c128 & 1];
      if (c128 < 7)
        stage_k23(Khi, Klo, krow0 + (size_t)(c128+1)*128, col0,
                  sK[(c128+1)&1], wave, drow, dseg);
      {
        const int mb = wave*16;
        f32x4 acc; acc[0]=0.f; acc[1]=0.f; acc[2]=0.f; acc[3]=0.f;
        #pragma unroll
        for (int ks = 0; ks < 2; ks++) {
          int phys = (mb + r)*64 + (((ks*4 + q) ^ sw))*8;
          bf16x8 kh = *(const bf16x8*)(cur + phys);
          bf16x8 kl = *(const bf16x8*)(cur + 8192 + phys);
          acc = MFMA16(qh[ks], kh, acc);
          acc = MFMA16(qh[ks], kl, acc);
          acc = MFMA16(ql[ks], kh, acc);
        }
        #pragma unroll
        for (int t = 0; t < 4; t++)
          slab[(q*4+t)*S23 + c128*128 + mb + r] = acc[t] * ATT_SCALE;
      }
      __syncthreads();
    }
    if (hh < 7) {   // prefetch next head's Q + K chunk 0 (overlaps softmax)
      int ncol = (h+1)*HD;
      stage_q23(Qhi, Qlo, qrow0, ncol, sQ, wave, drow, dseg);
      stage_k23(Khi, Klo, krow0, ncol, sK[0], wave, drow, dseg);
    }
    // ---- softmax over m (1024) per row; 32 threads per row
    const int n = tid >> 5, c = tid & 31;
    float mx = -1e30f;
    #pragma unroll 8
    for (int j = 0; j < 32; j++)
      mx = fmaxf(mx, slab[n*S23 + c + j*32]);
    red[tid] = mx;
    __syncthreads();
    if (tid < 16) {
      float m2 = red[tid*32];
      for (int j = 1; j < 32; j++) m2 = fmaxf(m2, red[tid*32 + j]);
      gmax[tid] = m2;
    }
    __syncthreads();
    const float gm = gmax[n];
    float s = 0.f;
    #pragma unroll 8
    for (int j = 0; j < 32; j++) {
      int idx = n*S23 + c + j*32;
      float p = __expf(slab[idx] - gm);
      slab[idx] = p;
      s += p;
    }
    red[tid] = s;
    __syncthreads();
    if (tid < 16) {
      float s2 = 0.f;
      for (int j = 0; j < 32; j++) s2 += red[tid*32 + j];
      gscale[tid] = 65535.0f / s2;
    }
    __syncthreads();
    const float sc = gscale[n];
    const size_t pb = ((size_t)((b*NH + h)*SEQ) + n0 + n)*SEQ;
    #pragma unroll
    for (int j = 0; j < 4; j++) {
      int m0 = (j*32 + c)*8;
      float4 v0 = *(const float4*)&slab[n*S23 + m0];
      float4 v1 = *(const float4*)&slab[n*S23 + m0 + 4];
      unsigned int u0 = (unsigned)(v0.x*sc + 0.5f) | ((unsigned)(v0.y*sc + 0.5f) << 16);
      unsigned int u1 = (unsigned)(v0.z*sc + 0.5f) | ((unsigned)(v0.w*sc + 0.5f) << 16);
      unsigned int u2 = (unsigned)(v1.x*sc + 0.5f) | ((unsigned)(v1.y*sc + 0.5f) << 16);
      unsigned int u3 = (unsigned)(v1.z*sc + 0.5f) | ((unsigned)(v1.w*sc + 0.5f) << 16);
      *(uint4*)(P + pb + m0) = make_uint4(u0, u1, u2, u3);
    }
  }
}

// ---------------------------------------------------------------------------
// K_attn: dequant-transpose P[b][h][n][m] u16 -> attn[b][n][m][h] f32.
// One thread per (b,n,m): 16 coalesced u16 loads, 4 contiguous float4 stores.
// ---------------------------------------------------------------------------
__global__ __launch_bounds__(256) void k_attn_write(
    const unsigned short* __restrict__ P, float* __restrict__ attn)
{
  int T = blockIdx.x*256 + threadIdx.x;
  int b = T >> 20, rem = T & 1048575;
  int n = rem >> 10, m = rem & 1023;
  const size_t pb = ((size_t)(b*NH)*SEQ + n)*SEQ + m;
  float v[16];
  #pragma unroll
  for (int h = 0; h < 16; h++)
    v[h] = (float)P[pb + (size_t)h*SEQ*SEQ] * (1.0f/65535.0f);
  size_t ob = ((size_t)(b*SEQ + n)*SEQ + m)*16;
  #pragma unroll
  for (int g = 0; g < 4; g++)
    *(float4*)(attn + ob + g*4) = make_float4(v[g*4], v[g*4+1], v[g*4+2], v[g*4+3]);
}

// ---------------------------------------------------------------------------
// K4: PV gemm per (b,h):  OA[n][d] = (1/65535) * sum_m P_u16[n][m] * V[m][d]
// 64n x 64d per block (512 blocks); P split exactly into two bf16 planes.
// ---------------------------------------------------------------------------
__global__ __launch_bounds__(256) void k_pv(
    const unsigned short* __restrict__ P,
    const unsigned short* __restrict__ Vthi, const unsigned short* __restrict__ Vtlo,
    unsigned short* __restrict__ OAhi, unsigned short* __restrict__ OAlo)
{
  int nt = blockIdx.x, h = blockIdx.y, b = blockIdx.z;
  int n0 = nt * 64;
  __shared__ unsigned short sPa[64*32], sPb[64*32], sVh[64*32], sVl[64*32];
  const int tid = threadIdx.x, lane = tid & 63, wave = tid >> 6;
  const int wm = wave & 1, wn = wave >> 1;
  const int r = lane & 15, q = lane >> 4;
  const int crow = lane >> 2, ccol = (lane & 3) * 8;
  const size_t pbase = ((size_t)(b*NH + h))*SEQ*SEQ;
  const size_t vbase = ((size_t)(b*NH + h))*HD*SEQ;

  f32x4 acc[2][2];
  #pragma unroll
  for (int i = 0; i < 2; i++)
    #pragma unroll
    for (int j = 0; j < 2; j++) {
      acc[i][j][0]=0.f; acc[i][j][1]=0.f; acc[i][j][2]=0.f; acc[i][j][3]=0.f;
    }

  for (int k0 = 0; k0 < SEQ; k0 += 32) {
    #pragma unroll
    for (int t = 0; t < 2; t++) {
      int c = wave + t*4;
      const unsigned short* gb = (c < 4) ? Vthi : Vtlo;
      unsigned short* sb = (c < 4) ? (unsigned short*)sVh : (unsigned short*)sVl;
      int rr = c & 3;
      int row = rr*16 + crow;
      gl_lds16(gb + vbase + (size_t)row*SEQ + k0 + ccol, sb + rr*512);
    }
    {
      int row = tid >> 2, ch = (tid & 3) * 8;
      uint4 v = *(const uint4*)(P + pbase + (size_t)(n0 + row)*SEQ + k0 + ch);
      unsigned int wds[4] = {v.x, v.y, v.z, v.w};
      unsigned int pa[4], pb4[4];
      #pragma unroll
      for (int e = 0; e < 4; e++) {
        unsigned int lo16 = wds[e] & 0xFFFFu;
        unsigned int hi16 = wds[e] >> 16;
        unsigned int a0 = __builtin_bit_cast(uint32_t, (float)(lo16 & 0xFF00u)) >> 16;
        unsigned int b0 = __builtin_bit_cast(uint32_t, (float)(lo16 & 0x00FFu)) >> 16;
        unsigned int a1 = __builtin_bit_cast(uint32_t, (float)(hi16 & 0xFF00u)) >> 16;
        unsigned int b1 = __builtin_bit_cast(uint32_t, (float)(hi16 & 0x00FFu)) >> 16;
        pa[e]  = a0 | (a1 << 16);
        pb4[e] = b0 | (b1 << 16);
      }
      *(uint4*)(sPa + row*32 + ch) = make_uint4(pa[0],pa[1],pa[2],pa[3]);
      *(uint4*)(sPb + row*32 + ch) = make_uint4(pb4[0],pb4[1],pb4[2],pb4[3]);
    }
    __syncthreads();
    bf16x8 pa[2], pb2[2], vh[2], vl[2];
    #pragma unroll
    for (int i = 0; i < 2; i++) {
      int off = (wm*32 + i*16 + r)*32 + q*8;
      pa[i]  = *(const bf16x8*)(sPa + off);
      pb2[i] = *(const bf16x8*)(sPb + off);
    }
    #pragma unroll
    for (int j = 0; j < 2; j++) {
      int off = (wn*32 + j*16 + r)*32 + q*8;
      vh[j] = *(const bf16x8*)(sVh + off);
      vl[j] = *(const bf16x8*)(sVl + off);
    }
    #pragma unroll
    for (int i = 0; i < 2; i++)
      #pragma unroll
      for (int j = 0; j < 2; j++) {
        acc[i][j] = MFMA16(pa[i],  vh[j], acc[i][j]);
        acc[i][j] = MFMA16(pb2[i], vh[j], acc[i][j]);
        acc[i][j] = MFMA16(pa[i],  vl[j], acc[i][j]);
      }
    __syncthreads();
  }
  #pragma unroll
  for (int i = 0; i < 2; i++)
    #pragma unroll
    for (int t = 0; t < 4; t++) {
      int nn = n0 + wm*32 + i*16 + q*4 + t;
      #pragma unroll
      for (int j = 0; j < 2; j++) {
        int d = wn*32 + j*16 + r;
        float val = acc[i][j][t] * (1.0f/65535.0f);
        size_t o = (size_t)(b*SEQ + nn)*CDIM + h*HD + d;
        unsigned short hb = f2bf(val);
        OAhi[o] = hb; OAlo[o] = f2bf(val - bf2f(hb));
      }
    }
}

// ---------------------------------------------------------------------------
extern "C" void kernel_launch(void* const* d_in, const int* in_sizes, int n_in,
                              void* d_out, int out_size, void* d_ws, size_t ws_size,
                              hipStream_t stream)
{
  const float* x   = (const float*)d_in[0];
  const float* Wq  = (const float*)d_in[1];
  const float* bq  = (const float*)d_in[2];
  const float* Wkv = (const float*)d_in[3];
  const float* bkv = (const float*)d_in[4];
  const float* Wp  = (const float*)d_in[5];
  const float* bp  = (const float*)d_in[6];

  float* out  = (float*)d_out;
  float* attn = out + (size_t)ROWS*CDIM;

  char* w = (char*)d_ws;
  unsigned short* Xhi  = (unsigned short*)w; w += (size_t)ROWS*CDIM*2;
  unsigned short* Xlo  = (unsigned short*)w; w += (size_t)ROWS*CDIM*2;
  unsigned short* Whi  = (unsigned short*)w; w += (size_t)4096*CDIM*2;
  unsigned short* Wlo  = (unsigned short*)w; w += (size_t)4096*CDIM*2;
  unsigned short* Qhi  = (unsigned short*)w; w += (size_t)ROWS*CDIM*2;
  unsigned short* Qlo  = (unsigned short*)w; w += (size_t)ROWS*CDIM*2;
  unsigned short* Khi  = (unsigned short*)w; w += (size_t)ROWS*CDIM*2;
  unsigned short* Klo  = (unsigned short*)w; w += (size_t)ROWS*CDIM*2;
  unsigned short* Vthi = (unsigned short*)w; w += (size_t)NB*NH*HD*SEQ*2;
  unsigned short* Vtlo = (unsigned short*)w; w += (size_t)NB*NH*HD*SEQ*2;
  unsigned short* OAhi = (unsigned short*)w; w += (size_t)ROWS*CDIM*2;
  unsigned short* OAlo = (unsigned short*)w; w += (size_t)ROWS*CDIM*2;
  unsigned short* P    = (unsigned short*)w; w += (size_t)NB*NH*SEQ*SEQ*2;

  k_convert<<<dim3((ROWS*CDIM + 4096*CDIM)/256), 256, 0, stream>>>(
      x, Wq, Wkv, Wp, Xhi, Xlo, Whi, Wlo);

  k_gemm_qkv<<<dim3(3072/128, 2048/128), 256, 0, stream>>>(
      Xhi, Xlo, Whi, Wlo, bq, bkv, Qhi, Qlo, Khi, Klo, Vthi, Vtlo);

  k_logits_softmax<<<dim3(SEQ/16, 2, NB), 512, 0, stream>>>(
      Qhi, Qlo, Khi, Klo, P);

  k_pv<<<dim3(SEQ/64, NH, NB), 256, 0, stream>>>(P, Vthi, Vtlo, OAhi, OAlo);

  k_gemm_out<<<dim3(1024/64, 2048/64), 256, 0, stream>>>(
      OAhi, OAlo, Whi + (size_t)3072*CDIM, Wlo + (size_t)3072*CDIM, bp, out);

  k_attn_write<<<dim3((NB*SEQ*SEQ)/256), 256, 0, stream>>>(P, attn);
}

// Round 2
// 394.531 us; speedup vs baseline: 1.0619x; 1.0393x over previous
//
#include <hip/hip_runtime.h>
#include <hip/hip_bf16.h>
#include <stdint.h>

// ---------------------------------------------------------------------------
// MultiHeadAttention on MI355X (gfx950).
// b=2, n=1024, DIM=1024, H=16, dh=64.  Outputs: out (2M f32) ++ attn (33.5M f32).
// GEMMs: bf16 MFMA 16x16x32, hi/lo split (3 MFMAs) => ~fp32 accuracy.
// R3: fused logits+softmax -> normalized u16 P; attn via transpose-dequant.
// R4: k_logits_softmax 512 thr.  (91 us: still latency-bound, ~104 barriers.)
// R5: k_logits_softmax rewritten as two-pass register softmax:
//     block = 32 n-rows x one (b,h); swapped mfma(K,Q) puts each n-row's
//     logits lane-local; pass 1 = online max/sum in regs; pass 2 recomputes
//     logits (bitwise identical) and writes u16 P directly.  No f32 slab:
//     LDS 134K->74K => 2 blocks/CU; barriers/block 104 -> ~19.
//     ATT_SCALE folded into Q at the QKV epilogue (exact 2^-3).
// ---------------------------------------------------------------------------

#define NB   2
#define SEQ  1024
#define CDIM 1024
#define NH   16
#define HD   64
#define ROWS (NB*SEQ)          // 2048
#define ATT_SCALE 0.125f       // 64^-0.5

typedef __attribute__((ext_vector_type(8))) short bf16x8;
typedef __attribute__((ext_vector_type(4))) float f32x4;

#define MFMA16(a,b,c) __builtin_amdgcn_mfma_f32_16x16x32_bf16((a),(b),(c),0,0,0)

static __device__ __forceinline__ unsigned short f2bf(float f) {
  uint32_t x = __builtin_bit_cast(uint32_t, f);
  return (unsigned short)((x + 0x7fffu + ((x >> 16) & 1u)) >> 16);   // RTN-even
}
static __device__ __forceinline__ float bf2f(unsigned short u) {
  uint32_t x = ((uint32_t)u) << 16;
  return __builtin_bit_cast(float, x);
}

// async global->LDS DMA, 16B/lane; lds dest = wave-uniform base + lane*16
static __device__ __forceinline__ void gl_lds16(const unsigned short* g,
                                                unsigned short* l) {
  __builtin_amdgcn_global_load_lds(
      (const __attribute__((address_space(1))) unsigned int*)g,
      (__attribute__((address_space(3))) unsigned int*)l,
      16, 0, 0);
}

// ---------------------------------------------------------------------------
// K0: fp32 -> bf16 hi/lo split for x and concatenated W = [Wq; Wkv; Wp]
// ---------------------------------------------------------------------------
__global__ __launch_bounds__(256) void k_convert(
    const float* __restrict__ x, const float* __restrict__ Wq,
    const float* __restrict__ Wkv, const float* __restrict__ Wp,
    unsigned short* __restrict__ Xhi, unsigned short* __restrict__ Xlo,
    unsigned short* __restrict__ Whi, unsigned short* __restrict__ Wlo)
{
  const int NX = ROWS * CDIM;
  const int NW = 4096 * CDIM;
  int i = blockIdx.x * 256 + threadIdx.x;
  if (i < NX) {
    float f = x[i];
    unsigned short h = f2bf(f);
    Xhi[i] = h; Xlo[i] = f2bf(f - bf2f(h));
  } else if (i < NX + NW) {
    int w = i - NX;
    int j = w >> 10, c = w & 1023;
    float f = (j < 1024) ? Wq[(size_t)j*1024 + c]
            : (j < 3072) ? Wkv[(size_t)(j-1024)*1024 + c]
                         : Wp[(size_t)(j-3072)*1024 + c];
    unsigned short h = f2bf(f);
    Whi[w] = h; Wlo[w] = f2bf(f - bf2f(h));
  }
}

// ---------------------------------------------------------------------------
// Templated NT-GEMM core (split bf16, BK=32, 256 threads = 2x2 waves)
// ---------------------------------------------------------------------------
struct EpiQKV {
  const float* bq; const float* bkv;
  unsigned short *Qhi, *Qlo, *Khi, *Klo, *Vthi, *Vtlo;
  __device__ __forceinline__ void operator()(int m, int n, float v) const {
    if (n < 1024) {                       // Q (pre-scaled by ATT_SCALE)
      v = (v + bq[n]) * ATT_SCALE;
      unsigned short h = f2bf(v);
      size_t o = (size_t)m*1024 + n;
      Qhi[o] = h; Qlo[o] = f2bf(v - bf2f(h));
    } else if (n < 2048) {                // K
      v += bkv[n - 1024];
      size_t o = (size_t)m*1024 + (n - 1024);
      unsigned short h = f2bf(v);
      Khi[o] = h; Klo[o] = f2bf(v - bf2f(h));
    } else {                              // V -> transposed [b][h][d][m]
      v += bkv[n - 1024];
      int c = n - 2048;
      int hh = c >> 6, d = c & 63;
      int b = m >> 10, mm = m & 1023;
      size_t o = ((size_t)((b*NH + hh)*HD + d))*SEQ + mm;
      unsigned short h = f2bf(v);
      Vthi[o] = h; Vtlo[o] = f2bf(v - bf2f(h));
    }
  }
};
struct EpiOut {
  const float* bp; float* out;
  __device__ __forceinline__ void operator()(int m, int n, float v) const {
    out[(size_t)m*1024 + n] = v + bp[n];
  }
};

template <int BM, int BN, class Epi>
__device__ __forceinline__ void gemm_core(
    const unsigned short* __restrict__ Ahi, const unsigned short* __restrict__ Alo, int lda,
    const unsigned short* __restrict__ Bhi, const unsigned short* __restrict__ Blo, int ldb,
    int K, const Epi& epi)
{
  constexpr int FM = BM/32, FN = BN/32;
  constexpr int CA = BM/16, CB = BN/16;
  constexpr int TOT = 2*(CA+CB);
  __shared__ unsigned short sAh[BM*32], sAl[BM*32], sBh[BN*32], sBl[BN*32];
  const int tid  = threadIdx.x;
  const int lane = tid & 63, wave = tid >> 6;
  const int wm = wave & 1, wn = wave >> 1;
  const int bn = blockIdx.x * BN, bm = blockIdx.y * BM;
  const int r = lane & 15, q = lane >> 4;
  const int crow = lane >> 2, ccol = (lane & 3) * 8;

  f32x4 acc[FM][FN];
  #pragma unroll
  for (int i = 0; i < FM; i++)
    #pragma unroll
    for (int j = 0; j < FN; j++) {
      acc[i][j][0]=0.f; acc[i][j][1]=0.f; acc[i][j][2]=0.f; acc[i][j][3]=0.f;
    }

  for (int k0 = 0; k0 < K; k0 += 32) {
    #pragma unroll
    for (int t = 0; t < TOT/4; t++) {
      int c = wave + t*4;
      const unsigned short* gb; unsigned short* sb; int rr, grow, ld;
      if (c < CA)            { gb=Ahi; sb=sAh; rr=c;         grow=bm; ld=lda; }
      else if (c < 2*CA)     { gb=Alo; sb=sAl; rr=c-CA;      grow=bm; ld=lda; }
      else if (c < 2*CA+CB)  { gb=Bhi; sb=sBh; rr=c-2*CA;    grow=bn; ld=ldb; }
      else                   { gb=Blo; sb=sBl; rr=c-2*CA-CB; grow=bn; ld=ldb; }
      int row = rr*16 + crow;
      gl_lds16(gb + (size_t)(grow + row)*ld + k0 + ccol, sb + rr*512);
    }
    __syncthreads();
    bf16x8 ah[FM], al[FM], bh[FN], bl[FN];
    #pragma unroll
    for (int i = 0; i < FM; i++) {
      int oa = (wm*(BM/2) + i*16 + r)*32 + q*8;
      ah[i] = *(const bf16x8*)(sAh + oa);
      al[i] = *(const bf16x8*)(sAl + oa);
    }
    #pragma unroll
    for (int j = 0; j < FN; j++) {
      int ob = (wn*(BN/2) + j*16 + r)*32 + q*8;
      bh[j] = *(const bf16x8*)(sBh + ob);
      bl[j] = *(const bf16x8*)(sBl + ob);
    }
    #pragma unroll
    for (int i = 0; i < FM; i++)
      #pragma unroll
      for (int j = 0; j < FN; j++) {
        acc[i][j] = MFMA16(ah[i], bh[j], acc[i][j]);
        acc[i][j] = MFMA16(ah[i], bl[j], acc[i][j]);
        acc[i][j] = MFMA16(al[i], bh[j], acc[i][j]);
      }
    __syncthreads();
  }
  #pragma unroll
  for (int i = 0; i < FM; i++)
    #pragma unroll
    for (int j = 0; j < FN; j++)
      #pragma unroll
      for (int t = 0; t < 4; t++)
        epi(bm + wm*(BM/2) + i*16 + q*4 + t, bn + wn*(BN/2) + j*16 + r, acc[i][j][t]);
}

__global__ __launch_bounds__(256) void k_gemm_qkv(
    const unsigned short* Xhi, const unsigned short* Xlo,
    const unsigned short* Whi, const unsigned short* Wlo,
    const float* bq, const float* bkv,
    unsigned short* Qhi, unsigned short* Qlo,
    unsigned short* Khi, unsigned short* Klo,
    unsigned short* Vthi, unsigned short* Vtlo)
{
  EpiQKV e{bq, bkv, Qhi, Qlo, Khi, Klo, Vthi, Vtlo};
  gemm_core<128,128>(Xhi, Xlo, CDIM, Whi, Wlo, CDIM, CDIM, e);
}

__global__ __launch_bounds__(256) void k_gemm_out(
    const unsigned short* OAhi, const unsigned short* OAlo,
    const unsigned short* Wphi, const unsigned short* Wplo,
    const float* bp, float* out)
{
  EpiOut e{bp, out};
  gemm_core<64,64>(OAhi, OAlo, CDIM, Wphi, Wplo, CDIM, CDIM, e);
}

// ---------------------------------------------------------------------------
// K23: two-pass register softmax -> normalized u16 P in [b][h][n][m].
// Block = 32 n-rows x one (b,h); 512 thr (8 waves).  K streamed twice in
// 128-m chunks (double-buffered, XOR-swizzled LDS).  mfma(K,Q): lane holds
// 4 m-values for n = nf*16 + (lane&15); pass 1 online max/sum; pass 2
// recomputes logits bitwise-identically, quantizes, stores u16 directly.
// ---------------------------------------------------------------------------
__global__ __launch_bounds__(512, 4) void k_logits_softmax(
    const unsigned short* __restrict__ Qhi, const unsigned short* __restrict__ Qlo,
    const unsigned short* __restrict__ Khi, const unsigned short* __restrict__ Klo,
    unsigned short* __restrict__ P)
{
  const int nt = blockIdx.x, h = blockIdx.y, b = blockIdx.z;
  const int n0 = nt*32;
  const int col0 = h*HD;
  __shared__ unsigned short sQ[2*32*64];       // [plane][32n x 64k] swizzled 8K
  __shared__ unsigned short sK[2][2*128*64];   // [buf][plane][128m x 64k] 64K
  __shared__ float redm[8][32], reds[8][32];   // per-wave partials
  __shared__ float gm_s[32], sc_s[32];
  const int tid = threadIdx.x, lane = tid & 63, wave = tid >> 6;
  const int r = lane & 15, q = lane >> 4;
  const int drow = lane >> 3, dseg = (lane & 7) ^ drow;   // DMA swizzle
  const int sw = r & 7;                                   // read swizzle
  const size_t qrow0 = (size_t)b*SEQ + n0;
  const size_t krow0 = (size_t)b*SEQ;

  auto stageK = [&](int c, int buf) {
    unsigned short* dst = sK[buf];
    #pragma unroll
    for (int u = 0; u < 4; u++) {
      int cc = wave*4 + u;                 // 0..31
      int p = cc >> 4, t = cc & 15;
      const unsigned short* g = p ? Klo : Khi;
      gl_lds16(g + (krow0 + (size_t)c*128 + t*8 + drow)*CDIM + col0 + dseg*8,
               dst + p*8192 + t*512);
    }
  };

  {   // stage Q (once) + K chunk 0
    int p = wave >> 2, t = wave & 3;
    const unsigned short* g = p ? Qlo : Qhi;
    gl_lds16(g + (qrow0 + t*8 + drow)*CDIM + col0 + dseg*8,
             sQ + p*2048 + t*512);
    stageK(0, 0);
  }
  __syncthreads();

  // Q fragments live in registers for the whole kernel
  bf16x8 qh[2][2], ql[2][2];
  #pragma unroll
  for (int nf = 0; nf < 2; nf++)
    #pragma unroll
    for (int ks = 0; ks < 2; ks++) {
      int phys = (nf*16 + r)*64 + (((ks*4 + q) ^ sw))*8;
      qh[nf][ks] = *(const bf16x8*)(sQ + phys);
      ql[nf][ks] = *(const bf16x8*)(sQ + 2048 + phys);
    }

  const int mb = wave*16;

  // ---- pass 1: online max/sum in registers
  float mx[2] = {-1e30f, -1e30f}, sm[2] = {0.f, 0.f};
  for (int c = 0; c < 8; c++) {
    if (c < 7) stageK(c+1, (c+1)&1);
    const unsigned short* cur = sK[c&1];
    bf16x8 kh[2], kl[2];
    #pragma unroll
    for (int ks = 0; ks < 2; ks++) {
      int phys = (mb + r)*64 + (((ks*4 + q) ^ sw))*8;
      kh[ks] = *(const bf16x8*)(cur + phys);
      kl[ks] = *(const bf16x8*)(cur + 8192 + phys);
    }
    #pragma unroll
    for (int nf = 0; nf < 2; nf++) {
      f32x4 acc; acc[0]=0.f; acc[1]=0.f; acc[2]=0.f; acc[3]=0.f;
      #pragma unroll
      for (int ks = 0; ks < 2; ks++) {
        acc = MFMA16(kh[ks], qh[nf][ks], acc);
        acc = MFMA16(kl[ks], qh[nf][ks], acc);
        acc = MFMA16(kh[ks], ql[nf][ks], acc);
      }
      float vmax = fmaxf(fmaxf(acc[0], acc[1]), fmaxf(acc[2], acc[3]));
      float mnew = fmaxf(mx[nf], vmax);
      sm[nf] = sm[nf]*__expf(mx[nf]-mnew)
             + __expf(acc[0]-mnew) + __expf(acc[1]-mnew)
             + __expf(acc[2]-mnew) + __expf(acc[3]-mnew);
      mx[nf] = mnew;
    }
    __syncthreads();
  }

  // ---- reduce (q-groups via shfl, waves via LDS); prefetch K chunk 0
  #pragma unroll
  for (int nf = 0; nf < 2; nf++) {
    #pragma unroll
    for (int off = 16; off <= 32; off <<= 1) {
      float mo = __shfl_xor(mx[nf], off);
      float so = __shfl_xor(sm[nf], off);
      float mn = fmaxf(mx[nf], mo);
      sm[nf] = sm[nf]*__expf(mx[nf]-mn) + so*__expf(mo-mn);
      mx[nf] = mn;
    }
  }
  if (q < 2) { redm[wave][q*16 + r] = mx[q]; reds[wave][q*16 + r] = sm[q]; }
  stageK(0, 0);
  __syncthreads();
  if (tid < 32) {
    float m2 = redm[0][tid], s2 = reds[0][tid];
    #pragma unroll
    for (int w2 = 1; w2 < 8; w2++) {
      float mo = redm[w2][tid], so = reds[w2][tid];
      float mn = fmaxf(m2, mo);
      s2 = s2*__expf(m2-mn) + so*__expf(mo-mn);
      m2 = mn;
    }
    gm_s[tid] = m2; sc_s[tid] = 65535.0f / s2;
  }
  __syncthreads();
  const float gm[2] = {gm_s[r], gm_s[16 + r]};
  const float sc[2] = {sc_s[r], sc_s[16 + r]};

  // ---- pass 2: recompute (bitwise identical), quantize, store
  const size_t pbase = ((size_t)(b*NH + h)*SEQ + n0)*SEQ;
  for (int c = 0; c < 8; c++) {
    if (c < 7) stageK(c+1, (c+1)&1);
    const unsigned short* cur = sK[c&1];
    bf16x8 kh[2], kl[2];
    #pragma unroll
    for (int ks = 0; ks < 2; ks++) {
      int phys = (mb + r)*64 + (((ks*4 + q) ^ sw))*8;
      kh[ks] = *(const bf16x8*)(cur + phys);
      kl[ks] = *(const bf16x8*)(cur + 8192 + phys);
    }
    #pragma unroll
    for (int nf = 0; nf < 2; nf++) {
      f32x4 acc; acc[0]=0.f; acc[1]=0.f; acc[2]=0.f; acc[3]=0.f;
      #pragma unroll
      for (int ks = 0; ks < 2; ks++) {
        acc = MFMA16(kh[ks], qh[nf][ks], acc);
        acc = MFMA16(kl[ks], qh[nf][ks], acc);
        acc = MFMA16(kh[ks], ql[nf][ks], acc);
      }
      unsigned int u0 = (unsigned)(__expf(acc[0]-gm[nf])*sc[nf] + 0.5f)
                      | ((unsigned)(__expf(acc[1]-gm[nf])*sc[nf] + 0.5f) << 16);
      unsigned int u1 = (unsigned)(__expf(acc[2]-gm[nf])*sc[nf] + 0.5f)
                      | ((unsigned)(__expf(acc[3]-gm[nf])*sc[nf] + 0.5f) << 16);
      *(uint2*)(P + pbase + (size_t)(nf*16 + r)*SEQ + c*128 + mb + q*4) =
          make_uint2(u0, u1);
    }
    __syncthreads();
  }
}

// ---------------------------------------------------------------------------
// K_attn: dequant-transpose P[b][h][n][m] u16 -> attn[b][n][m][h] f32.
// One thread per (b,n,m): 16 coalesced u16 loads, 4 contiguous float4 stores.
// ---------------------------------------------------------------------------
__global__ __launch_bounds__(256) void k_attn_write(
    const unsigned short* __restrict__ P, float* __restrict__ attn)
{
  int T = blockIdx.x*256 + threadIdx.x;
  int b = T >> 20, rem = T & 1048575;
  int n = rem >> 10, m = rem & 1023;
  const size_t pb = ((size_t)(b*NH)*SEQ + n)*SEQ + m;
  float v[16];
  #pragma unroll
  for (int h = 0; h < 16; h++)
    v[h] = (float)P[pb + (size_t)h*SEQ*SEQ] * (1.0f/65535.0f);
  size_t ob = ((size_t)(b*SEQ + n)*SEQ + m)*16;
  #pragma unroll
  for (int g = 0; g < 4; g++)
    *(float4*)(attn + ob + g*4) = make_float4(v[g*4], v[g*4+1], v[g*4+2], v[g*4+3]);
}

// ---------------------------------------------------------------------------
// K4: PV gemm per (b,h):  OA[n][d] = (1/65535) * sum_m P_u16[n][m] * V[m][d]
// 64n x 64d per block (512 blocks); P split exactly into two bf16 planes.
// ---------------------------------------------------------------------------
__global__ __launch_bounds__(256) void k_pv(
    const unsigned short* __restrict__ P,
    const unsigned short* __restrict__ Vthi, const unsigned short* __restrict__ Vtlo,
    unsigned short* __restrict__ OAhi, unsigned short* __restrict__ OAlo)
{
  int nt = blockIdx.x, h = blockIdx.y, b = blockIdx.z;
  int n0 = nt * 64;
  __shared__ unsigned short sPa[64*32], sPb[64*32], sVh[64*32], sVl[64*32];
  const int tid = threadIdx.x, lane = tid & 63, wave = tid >> 6;
  const int wm = wave & 1, wn = wave >> 1;
  const int r = lane & 15, q = lane >> 4;
  const int crow = lane >> 2, ccol = (lane & 3) * 8;
  const size_t pbase = ((size_t)(b*NH + h))*SEQ*SEQ;
  const size_t vbase = ((size_t)(b*NH + h))*HD*SEQ;

  f32x4 acc[2][2];
  #pragma unroll
  for (int i = 0; i < 2; i++)
    #pragma unroll
    for (int j = 0; j < 2; j++) {
      acc[i][j][0]=0.f; acc[i][j][1]=0.f; acc[i][j][2]=0.f; acc[i][j][3]=0.f;
    }

  for (int k0 = 0; k0 < SEQ; k0 += 32) {
    #pragma unroll
    for (int t = 0; t < 2; t++) {
      int c = wave + t*4;
      const unsigned short* gb = (c < 4) ? Vthi : Vtlo;
      unsigned short* sb = (c < 4) ? (unsigned short*)sVh : (unsigned short*)sVl;
      int rr = c & 3;
      int row = rr*16 + crow;
      gl_lds16(gb + vbase + (size_t)row*SEQ + k0 + ccol, sb + rr*512);
    }
    {
      int row = tid >> 2, ch = (tid & 3) * 8;
      uint4 v = *(const uint4*)(P + pbase + (size_t)(n0 + row)*SEQ + k0 + ch);
      unsigned int wds[4] = {v.x, v.y, v.z, v.w};
      unsigned int pa[4], pb4[4];
      #pragma unroll
      for (int e = 0; e < 4; e++) {
        unsigned int lo16 = wds[e] & 0xFFFFu;
        unsigned int hi16 = wds[e] >> 16;
        unsigned int a0 = __builtin_bit_cast(uint32_t, (float)(lo16 & 0xFF00u)) >> 16;
        unsigned int b0 = __builtin_bit_cast(uint32_t, (float)(lo16 & 0x00FFu)) >> 16;
        unsigned int a1 = __builtin_bit_cast(uint32_t, (float)(hi16 & 0xFF00u)) >> 16;
        unsigned int b1 = __builtin_bit_cast(uint32_t, (float)(hi16 & 0x00FFu)) >> 16;
        pa[e]  = a0 | (a1 << 16);
        pb4[e] = b0 | (b1 << 16);
      }
      *(uint4*)(sPa + row*32 + ch) = make_uint4(pa[0],pa[1],pa[2],pa[3]);
      *(uint4*)(sPb + row*32 + ch) = make_uint4(pb4[0],pb4[1],pb4[2],pb4[3]);
    }
    __syncthreads();
    bf16x8 pa[2], pb2[2], vh[2], vl[2];
    #pragma unroll
    for (int i = 0; i < 2; i++) {
      int off = (wm*32 + i*16 + r)*32 + q*8;
      pa[i]  = *(const bf16x8*)(sPa + off);
      pb2[i] = *(const bf16x8*)(sPb + off);
    }
    #pragma unroll
    for (int j = 0; j < 2; j++) {
      int off = (wn*32 + j*16 + r)*32 + q*8;
      vh[j] = *(const bf16x8*)(sVh + off);
      vl[j] = *(const bf16x8*)(sVl + off);
    }
    #pragma unroll
    for (int i = 0; i < 2; i++)
      #pragma unroll
      for (int j = 0; j < 2; j++) {
        acc[i][j] = MFMA16(pa[i],  vh[j], acc[i][j]);
        acc[i][j] = MFMA16(pb2[i], vh[j], acc[i][j]);
        acc[i][j] = MFMA16(pa[i],  vl[j], acc[i][j]);
      }
    __syncthreads();
  }
  #pragma unroll
  for (int i = 0; i < 2; i++)
    #pragma unroll
    for (int t = 0; t < 4; t++) {
      int nn = n0 + wm*32 + i*16 + q*4 + t;
      #pragma unroll
      for (int j = 0; j < 2; j++) {
        int d = wn*32 + j*16 + r;
        float val = acc[i][j][t] * (1.0f/65535.0f);
        size_t o = (size_t)(b*SEQ + nn)*CDIM + h*HD + d;
        unsigned short hb = f2bf(val);
        OAhi[o] = hb; OAlo[o] = f2bf(val - bf2f(hb));
      }
    }
}

// ---------------------------------------------------------------------------
extern "C" void kernel_launch(void* const* d_in, const int* in_sizes, int n_in,
                              void* d_out, int out_size, void* d_ws, size_t ws_size,
                              hipStream_t stream)
{
  const float* x   = (const float*)d_in[0];
  const float* Wq  = (const float*)d_in[1];
  const float* bq  = (const float*)d_in[2];
  const float* Wkv = (const float*)d_in[3];
  const float* bkv = (const float*)d_in[4];
  const float* Wp  = (const float*)d_in[5];
  const float* bp  = (const float*)d_in[6];

  float* out  = (float*)d_out;
  float* attn = out + (size_t)ROWS*CDIM;

  char* w = (char*)d_ws;
  unsigned short* Xhi  = (unsigned short*)w; w += (size_t)ROWS*CDIM*2;
  unsigned short* Xlo  = (unsigned short*)w; w += (size_t)ROWS*CDIM*2;
  unsigned short* Whi  = (unsigned short*)w; w += (size_t)4096*CDIM*2;
  unsigned short* Wlo  = (unsigned short*)w; w += (size_t)4096*CDIM*2;
  unsigned short* Qhi  = (unsigned short*)w; w += (size_t)ROWS*CDIM*2;
  unsigned short* Qlo  = (unsigned short*)w; w += (size_t)ROWS*CDIM*2;
  unsigned short* Khi  = (unsigned short*)w; w += (size_t)ROWS*CDIM*2;
  unsigned short* Klo  = (unsigned short*)w; w += (size_t)ROWS*CDIM*2;
  unsigned short* Vthi = (unsigned short*)w; w += (size_t)NB*NH*HD*SEQ*2;
  unsigned short* Vtlo = (unsigned short*)w; w += (size_t)NB*NH*HD*SEQ*2;
  unsigned short* OAhi = (unsigned short*)w; w += (size_t)ROWS*CDIM*2;
  unsigned short* OAlo = (unsigned short*)w; w += (size_t)ROWS*CDIM*2;
  unsigned short* P    = (unsigned short*)w; w += (size_t)NB*NH*SEQ*SEQ*2;

  k_convert<<<dim3((ROWS*CDIM + 4096*CDIM)/256), 256, 0, stream>>>(
      x, Wq, Wkv, Wp, Xhi, Xlo, Whi, Wlo);

  k_gemm_qkv<<<dim3(3072/128, 2048/128), 256, 0, stream>>>(
      Xhi, Xlo, Whi, Wlo, bq, bkv, Qhi, Qlo, Khi, Klo, Vthi, Vtlo);

  k_logits_softmax<<<dim3(SEQ/32, NH, NB), 512, 0, stream>>>(
      Qhi, Qlo, Khi, Klo, P);

  k_pv<<<dim3(SEQ/64, NH, NB), 256, 0, stream>>>(P, Vthi, Vtlo, OAhi, OAlo);

  k_gemm_out<<<dim3(1024/64, 2048/64), 256, 0, stream>>>(
      OAhi, OAlo, Whi + (size_t)3072*CDIM, Wlo + (size_t)3072*CDIM, bp, out);

  k_attn_write<<<dim3((NB*SEQ*SEQ)/256), 256, 0, stream>>>(P, attn);
}

// Round 3
// 385.392 us; speedup vs baseline: 1.0871x; 1.0237x over previous
//
#include <hip/hip_runtime.h>
#include <hip/hip_bf16.h>
#include <stdint.h>

// ---------------------------------------------------------------------------
// MultiHeadAttention on MI355X (gfx950).
// b=2, n=1024, DIM=1024, H=16, dh=64.  Outputs: out (2M f32) ++ attn (33.5M f32).
// GEMMs: bf16 MFMA 16x16x32, hi/lo split (3 MFMAs) => ~fp32 accuracy.
// R5: two-pass register softmax (K staged twice -> DMA-drain bound).
// R6: SINGLE-pass softmax: each 128-m chunk quantized against the row-wide
//     running max (1 barrier/chunk, redm double-buffered); per-(row,chunk)
//     fixup factor F = exp(m_c - m_final)/S written to a 1 MB table.
//     Consumers (k_pv, k_attn_write) apply prob = stored_u16 * F.
//     K staging + MFMA in the hot kernel HALVED.
//     Also: k_gemm_out 64x64 -> 128x64 tile, 8 waves (generalized gemm_core).
// ---------------------------------------------------------------------------

#define NB   2
#define SEQ  1024
#define CDIM 1024
#define NH   16
#define HD   64
#define ROWS (NB*SEQ)          // 2048
#define ATT_SCALE 0.125f       // 64^-0.5

typedef __attribute__((ext_vector_type(8))) short bf16x8;
typedef __attribute__((ext_vector_type(4))) float f32x4;

#define MFMA16(a,b,c) __builtin_amdgcn_mfma_f32_16x16x32_bf16((a),(b),(c),0,0,0)

static __device__ __forceinline__ unsigned short f2bf(float f) {
  uint32_t x = __builtin_bit_cast(uint32_t, f);
  return (unsigned short)((x + 0x7fffu + ((x >> 16) & 1u)) >> 16);   // RTN-even
}
static __device__ __forceinline__ float bf2f(unsigned short u) {
  uint32_t x = ((uint32_t)u) << 16;
  return __builtin_bit_cast(float, x);
}

// async global->LDS DMA, 16B/lane; lds dest = wave-uniform base + lane*16
static __device__ __forceinline__ void gl_lds16(const unsigned short* g,
                                                unsigned short* l) {
  __builtin_amdgcn_global_load_lds(
      (const __attribute__((address_space(1))) unsigned int*)g,
      (__attribute__((address_space(3))) unsigned int*)l,
      16, 0, 0);
}

// ---------------------------------------------------------------------------
// K0: fp32 -> bf16 hi/lo split for x and concatenated W = [Wq; Wkv; Wp]
// ---------------------------------------------------------------------------
__global__ __launch_bounds__(256) void k_convert(
    const float* __restrict__ x, const float* __restrict__ Wq,
    const float* __restrict__ Wkv, const float* __restrict__ Wp,
    unsigned short* __restrict__ Xhi, unsigned short* __restrict__ Xlo,
    unsigned short* __restrict__ Whi, unsigned short* __restrict__ Wlo)
{
  const int NX = ROWS * CDIM;
  const int NW = 4096 * CDIM;
  int i = blockIdx.x * 256 + threadIdx.x;
  if (i < NX) {
    float f = x[i];
    unsigned short h = f2bf(f);
    Xhi[i] = h; Xlo[i] = f2bf(f - bf2f(h));
  } else if (i < NX + NW) {
    int w = i - NX;
    int j = w >> 10, c = w & 1023;
    float f = (j < 1024) ? Wq[(size_t)j*1024 + c]
            : (j < 3072) ? Wkv[(size_t)(j-1024)*1024 + c]
                         : Wp[(size_t)(j-3072)*1024 + c];
    unsigned short h = f2bf(f);
    Whi[w] = h; Wlo[w] = f2bf(f - bf2f(h));
  }
}

// ---------------------------------------------------------------------------
// Templated NT-GEMM core (split bf16, BK=32, wave grid WM x WN)
// ---------------------------------------------------------------------------
struct EpiQKV {
  const float* bq; const float* bkv;
  unsigned short *Qhi, *Qlo, *Khi, *Klo, *Vthi, *Vtlo;
  __device__ __forceinline__ void operator()(int m, int n, float v) const {
    if (n < 1024) {                       // Q (pre-scaled by ATT_SCALE)
      v = (v + bq[n]) * ATT_SCALE;
      unsigned short h = f2bf(v);
      size_t o = (size_t)m*1024 + n;
      Qhi[o] = h; Qlo[o] = f2bf(v - bf2f(h));
    } else if (n < 2048) {                // K
      v += bkv[n - 1024];
      size_t o = (size_t)m*1024 + (n - 1024);
      unsigned short h = f2bf(v);
      Khi[o] = h; Klo[o] = f2bf(v - bf2f(h));
    } else {                              // V -> transposed [b][h][d][m]
      v += bkv[n - 1024];
      int c = n - 2048;
      int hh = c >> 6, d = c & 63;
      int b = m >> 10, mm = m & 1023;
      size_t o = ((size_t)((b*NH + hh)*HD + d))*SEQ + mm;
      unsigned short h = f2bf(v);
      Vthi[o] = h; Vtlo[o] = f2bf(v - bf2f(h));
    }
  }
};
struct EpiOut {
  const float* bp; float* out;
  __device__ __forceinline__ void operator()(int m, int n, float v) const {
    out[(size_t)m*1024 + n] = v + bp[n];
  }
};

template <int BM, int BN, int WM, int WN, class Epi>
__device__ __forceinline__ void gemm_core(
    const unsigned short* __restrict__ Ahi, const unsigned short* __restrict__ Alo, int lda,
    const unsigned short* __restrict__ Bhi, const unsigned short* __restrict__ Blo, int ldb,
    int K, const Epi& epi)
{
  constexpr int WAVES = WM*WN;
  constexpr int FM = BM/(WM*16), FN = BN/(WN*16);
  constexpr int CA = BM/16, CB = BN/16;
  constexpr int TOT = 2*(CA+CB);
  __shared__ unsigned short sAh[BM*32], sAl[BM*32], sBh[BN*32], sBl[BN*32];
  const int tid  = threadIdx.x;
  const int lane = tid & 63, wave = tid >> 6;
  const int wm = wave % WM, wn = wave / WM;
  const int bn = blockIdx.x * BN, bm = blockIdx.y * BM;
  const int r = lane & 15, q = lane >> 4;
  const int crow = lane >> 2, ccol = (lane & 3) * 8;

  f32x4 acc[FM][FN];
  #pragma unroll
  for (int i = 0; i < FM; i++)
    #pragma unroll
    for (int j = 0; j < FN; j++) {
      acc[i][j][0]=0.f; acc[i][j][1]=0.f; acc[i][j][2]=0.f; acc[i][j][3]=0.f;
    }

  for (int k0 = 0; k0 < K; k0 += 32) {
    #pragma unroll
    for (int t = 0; t < TOT/WAVES; t++) {
      int c = wave + t*WAVES;
      const unsigned short* gb; unsigned short* sb; int rr, grow, ld;
      if (c < CA)            { gb=Ahi; sb=sAh; rr=c;         grow=bm; ld=lda; }
      else if (c < 2*CA)     { gb=Alo; sb=sAl; rr=c-CA;      grow=bm; ld=lda; }
      else if (c < 2*CA+CB)  { gb=Bhi; sb=sBh; rr=c-2*CA;    grow=bn; ld=ldb; }
      else                   { gb=Blo; sb=sBl; rr=c-2*CA-CB; grow=bn; ld=ldb; }
      int row = rr*16 + crow;
      gl_lds16(gb + (size_t)(grow + row)*ld + k0 + ccol, sb + rr*512);
    }
    __syncthreads();
    bf16x8 ah[FM], al[FM], bh[FN], bl[FN];
    #pragma unroll
    for (int i = 0; i < FM; i++) {
      int oa = (wm*(BM/WM) + i*16 + r)*32 + q*8;
      ah[i] = *(const bf16x8*)(sAh + oa);
      al[i] = *(const bf16x8*)(sAl + oa);
    }
    #pragma unroll
    for (int j = 0; j < FN; j++) {
      int ob = (wn*(BN/WN) + j*16 + r)*32 + q*8;
      bh[j] = *(const bf16x8*)(sBh + ob);
      bl[j] = *(const bf16x8*)(sBl + ob);
    }
    #pragma unroll
    for (int i = 0; i < FM; i++)
      #pragma unroll
      for (int j = 0; j < FN; j++) {
        acc[i][j] = MFMA16(ah[i], bh[j], acc[i][j]);
        acc[i][j] = MFMA16(ah[i], bl[j], acc[i][j]);
        acc[i][j] = MFMA16(al[i], bh[j], acc[i][j]);
      }
    __syncthreads();
  }
  #pragma unroll
  for (int i = 0; i < FM; i++)
    #pragma unroll
    for (int j = 0; j < FN; j++)
      #pragma unroll
      for (int t = 0; t < 4; t++)
        epi(bm + wm*(BM/WM) + i*16 + q*4 + t, bn + wn*(BN/WN) + j*16 + r, acc[i][j][t]);
}

__global__ __launch_bounds__(256) void k_gemm_qkv(
    const unsigned short* Xhi, const unsigned short* Xlo,
    const unsigned short* Whi, const unsigned short* Wlo,
    const float* bq, const float* bkv,
    unsigned short* Qhi, unsigned short* Qlo,
    unsigned short* Khi, unsigned short* Klo,
    unsigned short* Vthi, unsigned short* Vtlo)
{
  EpiQKV e{bq, bkv, Qhi, Qlo, Khi, Klo, Vthi, Vtlo};
  gemm_core<128,128,2,2>(Xhi, Xlo, CDIM, Whi, Wlo, CDIM, CDIM, e);
}

__global__ __launch_bounds__(512) void k_gemm_out(
    const unsigned short* OAhi, const unsigned short* OAlo,
    const unsigned short* Wphi, const unsigned short* Wplo,
    const float* bp, float* out)
{
  EpiOut e{bp, out};
  gemm_core<128,64,4,2>(OAhi, OAlo, CDIM, Wphi, Wplo, CDIM, CDIM, e);
}

// ---------------------------------------------------------------------------
// K23: SINGLE-pass softmax -> u16 P (chunk-max quantized) + fixup table F.
// Block = 32 n-rows x one (b,h); 512 thr (8 waves).  K streamed ONCE in
// 128-m chunks (double-buffered, XOR-swizzled LDS).  mfma(K,Q): lane holds
// 4 m-values per nf.  Per chunk: row-wide max via shfl + LDS partials
// (redm double-buffered => 1 barrier/chunk); quantize vs running max;
// record m_c.  End: F[b,h,n,c] = exp(m_c - m_fin)/S;  prob = stored * F.
// ---------------------------------------------------------------------------
__global__ __launch_bounds__(512, 4) void k_logits_softmax(
    const unsigned short* __restrict__ Qhi, const unsigned short* __restrict__ Qlo,
    const unsigned short* __restrict__ Khi, const unsigned short* __restrict__ Klo,
    unsigned short* __restrict__ P, float* __restrict__ F)
{
  const int nt = blockIdx.x, h = blockIdx.y, b = blockIdx.z;
  const int n0 = nt*32;
  const int col0 = h*HD;
  __shared__ unsigned short sQ[2*32*64];       // [plane][32n x 64k] swizzled 8K
  __shared__ unsigned short sK[2][2*128*64];   // [buf][plane][128m x 64k] 64K
  __shared__ float redm[2][8][32];             // per-chunk wave partial max
  __shared__ float reds[8][32];                // final sum partials
  __shared__ float musd[32][8];                // m used per (row, chunk)
  const int tid = threadIdx.x, lane = tid & 63, wave = tid >> 6;
  const int r = lane & 15, q = lane >> 4;
  const int drow = lane >> 3, dseg = (lane & 7) ^ drow;   // DMA swizzle
  const int sw = r & 7;                                   // read swizzle
  const size_t qrow0 = (size_t)b*SEQ + n0;
  const size_t krow0 = (size_t)b*SEQ;

  auto stageK = [&](int c, int buf) {
    unsigned short* dst = sK[buf];
    #pragma unroll
    for (int u = 0; u < 4; u++) {
      int cc = wave*4 + u;                 // 0..31
      int p = cc >> 4, t = cc & 15;
      const unsigned short* g = p ? Klo : Khi;
      gl_lds16(g + (krow0 + (size_t)c*128 + t*8 + drow)*CDIM + col0 + dseg*8,
               dst + p*8192 + t*512);
    }
  };

  {   // stage Q (once) + K chunk 0
    int p = wave >> 2, t = wave & 3;
    const unsigned short* g = p ? Qlo : Qhi;
    gl_lds16(g + (qrow0 + t*8 + drow)*CDIM + col0 + dseg*8,
             sQ + p*2048 + t*512);
    stageK(0, 0);
  }
  __syncthreads();

  // Q fragments live in registers for the whole kernel
  bf16x8 qh[2][2], ql[2][2];
  #pragma unroll
  for (int nf = 0; nf < 2; nf++)
    #pragma unroll
    for (int ks = 0; ks < 2; ks++) {
      int phys = (nf*16 + r)*64 + (((ks*4 + q) ^ sw))*8;
      qh[nf][ks] = *(const bf16x8*)(sQ + phys);
      ql[nf][ks] = *(const bf16x8*)(sQ + 2048 + phys);
    }

  const int mb = wave*16;
  float m_run[2] = {-1e30f, -1e30f}, s_run[2] = {0.f, 0.f};
  const size_t pbase = ((size_t)(b*NH + h)*SEQ + n0)*SEQ;

  for (int c = 0; c < 8; c++) {
    if (c < 7) stageK(c+1, (c+1)&1);
    const unsigned short* cur = sK[c&1];
    bf16x8 kh[2], kl[2];
    #pragma unroll
    for (int ks = 0; ks < 2; ks++) {
      int phys = (mb + r)*64 + (((ks*4 + q) ^ sw))*8;
      kh[ks] = *(const bf16x8*)(cur + phys);
      kl[ks] = *(const bf16x8*)(cur + 8192 + phys);
    }
    f32x4 acc[2];
    #pragma unroll
    for (int nf = 0; nf < 2; nf++) {
      acc[nf][0]=0.f; acc[nf][1]=0.f; acc[nf][2]=0.f; acc[nf][3]=0.f;
      #pragma unroll
      for (int ks = 0; ks < 2; ks++) {
        acc[nf] = MFMA16(kh[ks], qh[nf][ks], acc[nf]);
        acc[nf] = MFMA16(kl[ks], qh[nf][ks], acc[nf]);
        acc[nf] = MFMA16(kh[ks], ql[nf][ks], acc[nf]);
      }
    }
    // wave-level row-chunk max (reduce over q groups)
    float wmax[2];
    #pragma unroll
    for (int nf = 0; nf < 2; nf++) {
      float v = fmaxf(fmaxf(acc[nf][0], acc[nf][1]), fmaxf(acc[nf][2], acc[nf][3]));
      v = fmaxf(v, __shfl_xor(v, 16));
      v = fmaxf(v, __shfl_xor(v, 32));
      wmax[nf] = v;
    }
    if (q == 0) { redm[c&1][wave][r] = wmax[0]; redm[c&1][wave][16+r] = wmax[1]; }
    __syncthreads();                       // 1 barrier/chunk
    #pragma unroll
    for (int nf = 0; nf < 2; nf++) {
      int row = nf*16 + r;
      float mc = redm[c&1][0][row];
      #pragma unroll
      for (int w2 = 1; w2 < 8; w2++) mc = fmaxf(mc, redm[c&1][w2][row]);
      float mnew = fmaxf(m_run[nf], mc);
      unsigned s0 = (unsigned)(__expf(acc[nf][0]-mnew)*65535.f + 0.5f);
      unsigned s1 = (unsigned)(__expf(acc[nf][1]-mnew)*65535.f + 0.5f);
      unsigned s2 = (unsigned)(__expf(acc[nf][2]-mnew)*65535.f + 0.5f);
      unsigned s3 = (unsigned)(__expf(acc[nf][3]-mnew)*65535.f + 0.5f);
      *(uint2*)(P + pbase + (size_t)row*SEQ + c*128 + mb + q*4) =
          make_uint2(s0 | (s1 << 16), s2 | (s3 << 16));
      s_run[nf] = s_run[nf]*__expf(m_run[nf]-mnew) + (float)(s0+s1+s2+s3);
      m_run[nf] = mnew;
      if (wave == 0 && q == 0) musd[row][c] = mnew;
    }
  }

  // ---- final sum reduction + F table
  #pragma unroll
  for (int nf = 0; nf < 2; nf++) {
    float s = s_run[nf];
    s += __shfl_xor(s, 16);
    s += __shfl_xor(s, 32);
    if (q == 0) reds[wave][nf*16 + r] = s;
  }
  __syncthreads();
  if (tid < 32) {
    int row = tid;
    float S = 0.f;
    #pragma unroll
    for (int w2 = 0; w2 < 8; w2++) S += reds[w2][row];
    float mfin = musd[row][7];
    float inv = 1.0f / S;
    size_t fb = ((size_t)(b*NH + h)*SEQ + n0 + row)*8;
    #pragma unroll
    for (int c = 0; c < 8; c++)
      F[fb + c] = __expf(musd[row][c] - mfin) * inv;
  }
}

// ---------------------------------------------------------------------------
// K_attn: dequant-transpose P[b][h][n][m] u16 * F -> attn[b][n][m][h] f32.
// One thread per (b,n,m): 16 coalesced u16 loads + 16 L2-hot F loads,
// 4 contiguous float4 stores.
// ---------------------------------------------------------------------------
__global__ __launch_bounds__(256) void k_attn_write(
    const unsigned short* __restrict__ P, const float* __restrict__ F,
    float* __restrict__ attn)
{
  int T = blockIdx.x*256 + threadIdx.x;
  int b = T >> 20, rem = T & 1048575;
  int n = rem >> 10, m = rem & 1023;
  int c = m >> 7;
  const size_t pb = ((size_t)(b*NH)*SEQ + n)*SEQ + m;
  const size_t fb = ((size_t)(b*NH)*SEQ + n)*8 + c;
  float v[16];
  #pragma unroll
  for (int h = 0; h < 16; h++)
    v[h] = (float)P[pb + (size_t)h*SEQ*SEQ] * F[fb + (size_t)h*SEQ*8];
  size_t ob = ((size_t)(b*SEQ + n)*SEQ + m)*16;
  #pragma unroll
  for (int g = 0; g < 4; g++)
    *(float4*)(attn + ob + g*4) = make_float4(v[g*4], v[g*4+1], v[g*4+2], v[g*4+3]);
}

// ---------------------------------------------------------------------------
// K4: PV gemm per (b,h):  OA[n][d] = sum_c F[n][c] * sum_{m in c} P_u16 * V
// 64n x 64d per block (512 blocks); exact byte-split planes of stored u16;
// per-chunk fold accF += acc * F (keeps bit-exact dequant).
// ---------------------------------------------------------------------------
__global__ __launch_bounds__(256) void k_pv(
    const unsigned short* __restrict__ P, const float* __restrict__ F,
    const unsigned short* __restrict__ Vthi, const unsigned short* __restrict__ Vtlo,
    unsigned short* __restrict__ OAhi, unsigned short* __restrict__ OAlo)
{
  int nt = blockIdx.x, h = blockIdx.y, b = blockIdx.z;
  int n0 = nt * 64;
  __shared__ unsigned short sPa[64*32], sPb[64*32], sVh[64*32], sVl[64*32];
  const int tid = threadIdx.x, lane = tid & 63, wave = tid >> 6;
  const int wm = wave & 1, wn = wave >> 1;
  const int r = lane & 15, q = lane >> 4;
  const int crow = lane >> 2, ccol = (lane & 3) * 8;
  const size_t pbase = ((size_t)(b*NH + h))*SEQ*SEQ;
  const size_t vbase = ((size_t)(b*NH + h))*HD*SEQ;
  const size_t fbase = ((size_t)(b*NH + h))*SEQ*8;

  f32x4 acc[2][2], accF[2][2];
  #pragma unroll
  for (int i = 0; i < 2; i++)
    #pragma unroll
    for (int j = 0; j < 2; j++) {
      acc[i][j][0]=0.f; acc[i][j][1]=0.f; acc[i][j][2]=0.f; acc[i][j][3]=0.f;
      accF[i][j][0]=0.f; accF[i][j][1]=0.f; accF[i][j][2]=0.f; accF[i][j][3]=0.f;
    }

  for (int k0 = 0; k0 < SEQ; k0 += 32) {
    #pragma unroll
    for (int t = 0; t < 2; t++) {
      int c = wave + t*4;
      const unsigned short* gb = (c < 4) ? Vthi : Vtlo;
      unsigned short* sb = (c < 4) ? (unsigned short*)sVh : (unsigned short*)sVl;
      int rr = c & 3;
      int row = rr*16 + crow;
      gl_lds16(gb + vbase + (size_t)row*SEQ + k0 + ccol, sb + rr*512);
    }
    {
      int row = tid >> 2, ch = (tid & 3) * 8;
      uint4 v = *(const uint4*)(P + pbase + (size_t)(n0 + row)*SEQ + k0 + ch);
      unsigned int wds[4] = {v.x, v.y, v.z, v.w};
      unsigned int pa[4], pb4[4];
      #pragma unroll
      for (int e = 0; e < 4; e++) {
        unsigned int lo16 = wds[e] & 0xFFFFu;
        unsigned int hi16 = wds[e] >> 16;
        unsigned int a0 = __builtin_bit_cast(uint32_t, (float)(lo16 & 0xFF00u)) >> 16;
        unsigned int b0 = __builtin_bit_cast(uint32_t, (float)(lo16 & 0x00FFu)) >> 16;
        unsigned int a1 = __builtin_bit_cast(uint32_t, (float)(hi16 & 0xFF00u)) >> 16;
        unsigned int b1 = __builtin_bit_cast(uint32_t, (float)(hi16 & 0x00FFu)) >> 16;
        pa[e]  = a0 | (a1 << 16);
        pb4[e] = b0 | (b1 << 16);
      }
      *(uint4*)(sPa + row*32 + ch) = make_uint4(pa[0],pa[1],pa[2],pa[3]);
      *(uint4*)(sPb + row*32 + ch) = make_uint4(pb4[0],pb4[1],pb4[2],pb4[3]);
    }
    __syncthreads();
    bf16x8 pa[2], pb2[2], vh[2], vl[2];
    #pragma unroll
    for (int i = 0; i < 2; i++) {
      int off = (wm*32 + i*16 + r)*32 + q*8;
      pa[i]  = *(const bf16x8*)(sPa + off);
      pb2[i] = *(const bf16x8*)(sPb + off);
    }
    #pragma unroll
    for (int j = 0; j < 2; j++) {
      int off = (wn*32 + j*16 + r)*32 + q*8;
      vh[j] = *(const bf16x8*)(sVh + off);
      vl[j] = *(const bf16x8*)(sVl + off);
    }
    #pragma unroll
    for (int i = 0; i < 2; i++)
      #pragma unroll
      for (int j = 0; j < 2; j++) {
        acc[i][j] = MFMA16(pa[i],  vh[j], acc[i][j]);
        acc[i][j] = MFMA16(pb2[i], vh[j], acc[i][j]);
        acc[i][j] = MFMA16(pa[i],  vl[j], acc[i][j]);
      }
    if ((k0 & 127) == 96) {                // end of 128-m chunk: fold with F
      int c = k0 >> 7;
      #pragma unroll
      for (int i = 0; i < 2; i++)
        #pragma unroll
        for (int t = 0; t < 4; t++) {
          int nn = n0 + wm*32 + i*16 + q*4 + t;
          float Fv = F[fbase + (size_t)nn*8 + c];
          #pragma unroll
          for (int j = 0; j < 2; j++) {
            accF[i][j][t] += acc[i][j][t] * Fv;
            acc[i][j][t] = 0.f;
          }
        }
    }
    __syncthreads();
  }
  #pragma unroll
  for (int i = 0; i < 2; i++)
    #pragma unroll
    for (int t = 0; t < 4; t++) {
      int nn = n0 + wm*32 + i*16 + q*4 + t;
      #pragma unroll
      for (int j = 0; j < 2; j++) {
        int d = wn*32 + j*16 + r;
        float val = accF[i][j][t];
        size_t o = (size_t)(b*SEQ + nn)*CDIM + h*HD + d;
        unsigned short hb = f2bf(val);
        OAhi[o] = hb; OAlo[o] = f2bf(val - bf2f(hb));
      }
    }
}

// ---------------------------------------------------------------------------
extern "C" void kernel_launch(void* const* d_in, const int* in_sizes, int n_in,
                              void* d_out, int out_size, void* d_ws, size_t ws_size,
                              hipStream_t stream)
{
  const float* x   = (const float*)d_in[0];
  const float* Wq  = (const float*)d_in[1];
  const float* bq  = (const float*)d_in[2];
  const float* Wkv = (const float*)d_in[3];
  const float* bkv = (const float*)d_in[4];
  const float* Wp  = (const float*)d_in[5];
  const float* bp  = (const float*)d_in[6];

  float* out  = (float*)d_out;
  float* attn = out + (size_t)ROWS*CDIM;

  char* w = (char*)d_ws;
  unsigned short* Xhi  = (unsigned short*)w; w += (size_t)ROWS*CDIM*2;
  unsigned short* Xlo  = (unsigned short*)w; w += (size_t)ROWS*CDIM*2;
  unsigned short* Whi  = (unsigned short*)w; w += (size_t)4096*CDIM*2;
  unsigned short* Wlo  = (unsigned short*)w; w += (size_t)4096*CDIM*2;
  unsigned short* Qhi  = (unsigned short*)w; w += (size_t)ROWS*CDIM*2;
  unsigned short* Qlo  = (unsigned short*)w; w += (size_t)ROWS*CDIM*2;
  unsigned short* Khi  = (unsigned short*)w; w += (size_t)ROWS*CDIM*2;
  unsigned short* Klo  = (unsigned short*)w; w += (size_t)ROWS*CDIM*2;
  unsigned short* Vthi = (unsigned short*)w; w += (size_t)NB*NH*HD*SEQ*2;
  unsigned short* Vtlo = (unsigned short*)w; w += (size_t)NB*NH*HD*SEQ*2;
  unsigned short* OAhi = (unsigned short*)w; w += (size_t)ROWS*CDIM*2;
  unsigned short* OAlo = (unsigned short*)w; w += (size_t)ROWS*CDIM*2;
  unsigned short* P    = (unsigned short*)w; w += (size_t)NB*NH*SEQ*SEQ*2;
  float*          Ftab = (float*)w;          w += (size_t)NB*NH*SEQ*8*4;

  k_convert<<<dim3((ROWS*CDIM + 4096*CDIM)/256), 256, 0, stream>>>(
      x, Wq, Wkv, Wp, Xhi, Xlo, Whi, Wlo);

  k_gemm_qkv<<<dim3(3072/128, 2048/128), 256, 0, stream>>>(
      Xhi, Xlo, Whi, Wlo, bq, bkv, Qhi, Qlo, Khi, Klo, Vthi, Vtlo);

  k_logits_softmax<<<dim3(SEQ/32, NH, NB), 512, 0, stream>>>(
      Qhi, Qlo, Khi, Klo, P, Ftab);

  k_pv<<<dim3(SEQ/64, NH, NB), 256, 0, stream>>>(P, Ftab, Vthi, Vtlo, OAhi, OAlo);

  k_gemm_out<<<dim3(1024/64, 2048/128), 512, 0, stream>>>(
      OAhi, OAlo, Whi + (size_t)3072*CDIM, Wlo + (size_t)3072*CDIM, bp, out);

  k_attn_write<<<dim3((NB*SEQ*SEQ)/256), 256, 0, stream>>>(P, Ftab, attn);
}

// Round 4
// 369.386 us; speedup vs baseline: 1.1342x; 1.0433x over previous
//
#include <hip/hip_runtime.h>
#include <hip/hip_bf16.h>
#include <stdint.h>

// ---------------------------------------------------------------------------
// MultiHeadAttention on MI355X (gfx950).
// b=2, n=1024, DIM=1024, H=16, dh=64.  Outputs: out (2M f32) ++ attn (33.5M f32).
// GEMMs: bf16 MFMA 16x16x32, hi/lo split (3 MFMAs) => ~fp32 accuracy.
// R6: single-pass softmax + F fixup table; k_gemm_out 128x64.
// R7: LDS XOR-swizzle in gemm_core / k_pv (old [row][32] layout was an
//     8-way bank conflict on every ds_read_b128/ds_write_b128: bank base
//     16*(row&1); 3.15M conflicts on k_gemm_qkv).  group ^= (row>>1)&3,
//     applied to BOTH the pre-swizzled global source of global_load_lds
//     (linear LDS dest) and the LDS reads.  Also k_gemm_qkv retiled
//     128x128 -> 128x64: grid 384 (1.5 blk/CU, 33% tail idle) -> 768
//     (exactly 3/CU, cross-block latency overlap).
// ---------------------------------------------------------------------------

#define NB   2
#define SEQ  1024
#define CDIM 1024
#define NH   16
#define HD   64
#define ROWS (NB*SEQ)          // 2048
#define ATT_SCALE 0.125f       // 64^-0.5

typedef __attribute__((ext_vector_type(8))) short bf16x8;
typedef __attribute__((ext_vector_type(4))) float f32x4;

#define MFMA16(a,b,c) __builtin_amdgcn_mfma_f32_16x16x32_bf16((a),(b),(c),0,0,0)

static __device__ __forceinline__ unsigned short f2bf(float f) {
  uint32_t x = __builtin_bit_cast(uint32_t, f);
  return (unsigned short)((x + 0x7fffu + ((x >> 16) & 1u)) >> 16);   // RTN-even
}
static __device__ __forceinline__ float bf2f(unsigned short u) {
  uint32_t x = ((uint32_t)u) << 16;
  return __builtin_bit_cast(float, x);
}

// async global->LDS DMA, 16B/lane; lds dest = wave-uniform base + lane*16
static __device__ __forceinline__ void gl_lds16(const unsigned short* g,
                                                unsigned short* l) {
  __builtin_amdgcn_global_load_lds(
      (const __attribute__((address_space(1))) unsigned int*)g,
      (__attribute__((address_space(3))) unsigned int*)l,
      16, 0, 0);
}

// ---------------------------------------------------------------------------
// K0: fp32 -> bf16 hi/lo split for x and concatenated W = [Wq; Wkv; Wp]
// ---------------------------------------------------------------------------
__global__ __launch_bounds__(256) void k_convert(
    const float* __restrict__ x, const float* __restrict__ Wq,
    const float* __restrict__ Wkv, const float* __restrict__ Wp,
    unsigned short* __restrict__ Xhi, unsigned short* __restrict__ Xlo,
    unsigned short* __restrict__ Whi, unsigned short* __restrict__ Wlo)
{
  const int NX = ROWS * CDIM;
  const int NW = 4096 * CDIM;
  int i = blockIdx.x * 256 + threadIdx.x;
  if (i < NX) {
    float f = x[i];
    unsigned short h = f2bf(f);
    Xhi[i] = h; Xlo[i] = f2bf(f - bf2f(h));
  } else if (i < NX + NW) {
    int w = i - NX;
    int j = w >> 10, c = w & 1023;
    float f = (j < 1024) ? Wq[(size_t)j*1024 + c]
            : (j < 3072) ? Wkv[(size_t)(j-1024)*1024 + c]
                         : Wp[(size_t)(j-3072)*1024 + c];
    unsigned short h = f2bf(f);
    Whi[w] = h; Wlo[w] = f2bf(f - bf2f(h));
  }
}

// ---------------------------------------------------------------------------
// Templated NT-GEMM core (split bf16, BK=32, wave grid WM x WN).
// LDS layout [row][32 u16] with group-XOR swizzle: 16B group g of row r
// lives at physical group g ^ ((r>>1)&3)  => quarter-wave b128 ops span
// all 8 bank-quads (2-way only = free).
// ---------------------------------------------------------------------------
struct EpiQKV {
  const float* bq; const float* bkv;
  unsigned short *Qhi, *Qlo, *Khi, *Klo, *Vthi, *Vtlo;
  __device__ __forceinline__ void operator()(int m, int n, float v) const {
    if (n < 1024) {                       // Q (pre-scaled by ATT_SCALE)
      v = (v + bq[n]) * ATT_SCALE;
      unsigned short h = f2bf(v);
      size_t o = (size_t)m*1024 + n;
      Qhi[o] = h; Qlo[o] = f2bf(v - bf2f(h));
    } else if (n < 2048) {                // K
      v += bkv[n - 1024];
      size_t o = (size_t)m*1024 + (n - 1024);
      unsigned short h = f2bf(v);
      Khi[o] = h; Klo[o] = f2bf(v - bf2f(h));
    } else {                              // V -> transposed [b][h][d][m]
      v += bkv[n - 1024];
      int c = n - 2048;
      int hh = c >> 6, d = c & 63;
      int b = m >> 10, mm = m & 1023;
      size_t o = ((size_t)((b*NH + hh)*HD + d))*SEQ + mm;
      unsigned short h = f2bf(v);
      Vthi[o] = h; Vtlo[o] = f2bf(v - bf2f(h));
    }
  }
};
struct EpiOut {
  const float* bp; float* out;
  __device__ __forceinline__ void operator()(int m, int n, float v) const {
    out[(size_t)m*1024 + n] = v + bp[n];
  }
};

template <int BM, int BN, int WM, int WN, class Epi>
__device__ __forceinline__ void gemm_core(
    const unsigned short* __restrict__ Ahi, const unsigned short* __restrict__ Alo, int lda,
    const unsigned short* __restrict__ Bhi, const unsigned short* __restrict__ Blo, int ldb,
    int K, const Epi& epi)
{
  constexpr int WAVES = WM*WN;
  constexpr int FM = BM/(WM*16), FN = BN/(WN*16);
  constexpr int CA = BM/16, CB = BN/16;
  constexpr int TOT = 2*(CA+CB);
  __shared__ unsigned short sAh[BM*32], sAl[BM*32], sBh[BN*32], sBl[BN*32];
  const int tid  = threadIdx.x;
  const int lane = tid & 63, wave = tid >> 6;
  const int wm = wave % WM, wn = wave / WM;
  const int bn = blockIdx.x * BN, bm = blockIdx.y * BM;
  const int r = lane & 15, q = lane >> 4;
  const int crow = lane >> 2;
  const int cgsw = ((lane & 3) ^ ((crow >> 1) & 3)) * 8;   // swizzled src group
  const int qsw = (q ^ ((r >> 1) & 3)) * 8;                // swizzled read group

  f32x4 acc[FM][FN];
  #pragma unroll
  for (int i = 0; i < FM; i++)
    #pragma unroll
    for (int j = 0; j < FN; j++) {
      acc[i][j][0]=0.f; acc[i][j][1]=0.f; acc[i][j][2]=0.f; acc[i][j][3]=0.f;
    }

  for (int k0 = 0; k0 < K; k0 += 32) {
    #pragma unroll
    for (int t = 0; t < TOT/WAVES; t++) {
      int c = wave + t*WAVES;
      const unsigned short* gb; unsigned short* sb; int rr, grow, ld;
      if (c < CA)            { gb=Ahi; sb=sAh; rr=c;         grow=bm; ld=lda; }
      else if (c < 2*CA)     { gb=Alo; sb=sAl; rr=c-CA;      grow=bm; ld=lda; }
      else if (c < 2*CA+CB)  { gb=Bhi; sb=sBh; rr=c-2*CA;    grow=bn; ld=ldb; }
      else                   { gb=Blo; sb=sBl; rr=c-2*CA-CB; grow=bn; ld=ldb; }
      int row = rr*16 + crow;
      gl_lds16(gb + (size_t)(grow + row)*ld + k0 + cgsw, sb + rr*512);
    }
    __syncthreads();
    bf16x8 ah[FM], al[FM], bh[FN], bl[FN];
    #pragma unroll
    for (int i = 0; i < FM; i++) {
      int oa = (wm*(BM/WM) + i*16 + r)*32 + qsw;
      ah[i] = *(const bf16x8*)(sAh + oa);
      al[i] = *(const bf16x8*)(sAl + oa);
    }
    #pragma unroll
    for (int j = 0; j < FN; j++) {
      int ob = (wn*(BN/WN) + j*16 + r)*32 + qsw;
      bh[j] = *(const bf16x8*)(sBh + ob);
      bl[j] = *(const bf16x8*)(sBl + ob);
    }
    #pragma unroll
    for (int i = 0; i < FM; i++)
      #pragma unroll
      for (int j = 0; j < FN; j++) {
        acc[i][j] = MFMA16(ah[i], bh[j], acc[i][j]);
        acc[i][j] = MFMA16(ah[i], bl[j], acc[i][j]);
        acc[i][j] = MFMA16(al[i], bh[j], acc[i][j]);
      }
    __syncthreads();
  }
  #pragma unroll
  for (int i = 0; i < FM; i++)
    #pragma unroll
    for (int j = 0; j < FN; j++)
      #pragma unroll
      for (int t = 0; t < 4; t++)
        epi(bm + wm*(BM/WM) + i*16 + q*4 + t, bn + wn*(BN/WN) + j*16 + r, acc[i][j][t]);
}

__global__ __launch_bounds__(256) void k_gemm_qkv(
    const unsigned short* Xhi, const unsigned short* Xlo,
    const unsigned short* Whi, const unsigned short* Wlo,
    const float* bq, const float* bkv,
    unsigned short* Qhi, unsigned short* Qlo,
    unsigned short* Khi, unsigned short* Klo,
    unsigned short* Vthi, unsigned short* Vtlo)
{
  EpiQKV e{bq, bkv, Qhi, Qlo, Khi, Klo, Vthi, Vtlo};
  gemm_core<128,64,2,2>(Xhi, Xlo, CDIM, Whi, Wlo, CDIM, CDIM, e);
}

__global__ __launch_bounds__(512) void k_gemm_out(
    const unsigned short* OAhi, const unsigned short* OAlo,
    const unsigned short* Wphi, const unsigned short* Wplo,
    const float* bp, float* out)
{
  EpiOut e{bp, out};
  gemm_core<128,64,4,2>(OAhi, OAlo, CDIM, Wphi, Wplo, CDIM, CDIM, e);
}

// ---------------------------------------------------------------------------
// K23: SINGLE-pass softmax -> u16 P (chunk-max quantized) + fixup table F.
// Block = 32 n-rows x one (b,h); 512 thr (8 waves).  K streamed ONCE in
// 128-m chunks (double-buffered, XOR-swizzled LDS).  mfma(K,Q): lane holds
// 4 m-values per nf.  Per chunk: row-wide max via shfl + LDS partials
// (redm double-buffered => 1 barrier/chunk); quantize vs running max;
// record m_c.  End: F[b,h,n,c] = exp(m_c - m_fin)/S;  prob = stored * F.
// ---------------------------------------------------------------------------
__global__ __launch_bounds__(512, 4) void k_logits_softmax(
    const unsigned short* __restrict__ Qhi, const unsigned short* __restrict__ Qlo,
    const unsigned short* __restrict__ Khi, const unsigned short* __restrict__ Klo,
    unsigned short* __restrict__ P, float* __restrict__ F)
{
  const int nt = blockIdx.x, h = blockIdx.y, b = blockIdx.z;
  const int n0 = nt*32;
  const int col0 = h*HD;
  __shared__ unsigned short sQ[2*32*64];       // [plane][32n x 64k] swizzled 8K
  __shared__ unsigned short sK[2][2*128*64];   // [buf][plane][128m x 64k] 64K
  __shared__ float redm[2][8][32];             // per-chunk wave partial max
  __shared__ float reds[8][32];                // final sum partials
  __shared__ float musd[32][8];                // m used per (row, chunk)
  const int tid = threadIdx.x, lane = tid & 63, wave = tid >> 6;
  const int r = lane & 15, q = lane >> 4;
  const int drow = lane >> 3, dseg = (lane & 7) ^ drow;   // DMA swizzle
  const int sw = r & 7;                                   // read swizzle
  const size_t qrow0 = (size_t)b*SEQ + n0;
  const size_t krow0 = (size_t)b*SEQ;

  auto stageK = [&](int c, int buf) {
    unsigned short* dst = sK[buf];
    #pragma unroll
    for (int u = 0; u < 4; u++) {
      int cc = wave*4 + u;                 // 0..31
      int p = cc >> 4, t = cc & 15;
      const unsigned short* g = p ? Klo : Khi;
      gl_lds16(g + (krow0 + (size_t)c*128 + t*8 + drow)*CDIM + col0 + dseg*8,
               dst + p*8192 + t*512);
    }
  };

  {   // stage Q (once) + K chunk 0
    int p = wave >> 2, t = wave & 3;
    const unsigned short* g = p ? Qlo : Qhi;
    gl_lds16(g + (qrow0 + t*8 + drow)*CDIM + col0 + dseg*8,
             sQ + p*2048 + t*512);
    stageK(0, 0);
  }
  __syncthreads();

  // Q fragments live in registers for the whole kernel
  bf16x8 qh[2][2], ql[2][2];
  #pragma unroll
  for (int nf = 0; nf < 2; nf++)
    #pragma unroll
    for (int ks = 0; ks < 2; ks++) {
      int phys = (nf*16 + r)*64 + (((ks*4 + q) ^ sw))*8;
      qh[nf][ks] = *(const bf16x8*)(sQ + phys);
      ql[nf][ks] = *(const bf16x8*)(sQ + 2048 + phys);
    }

  const int mb = wave*16;
  float m_run[2] = {-1e30f, -1e30f}, s_run[2] = {0.f, 0.f};
  const size_t pbase = ((size_t)(b*NH + h)*SEQ + n0)*SEQ;

  for (int c = 0; c < 8; c++) {
    if (c < 7) stageK(c+1, (c+1)&1);
    const unsigned short* cur = sK[c&1];
    bf16x8 kh[2], kl[2];
    #pragma unroll
    for (int ks = 0; ks < 2; ks++) {
      int phys = (mb + r)*64 + (((ks*4 + q) ^ sw))*8;
      kh[ks] = *(const bf16x8*)(cur + phys);
      kl[ks] = *(const bf16x8*)(cur + 8192 + phys);
    }
    f32x4 acc[2];
    #pragma unroll
    for (int nf = 0; nf < 2; nf++) {
      acc[nf][0]=0.f; acc[nf][1]=0.f; acc[nf][2]=0.f; acc[nf][3]=0.f;
      #pragma unroll
      for (int ks = 0; ks < 2; ks++) {
        acc[nf] = MFMA16(kh[ks], qh[nf][ks], acc[nf]);
        acc[nf] = MFMA16(kl[ks], qh[nf][ks], acc[nf]);
        acc[nf] = MFMA16(kh[ks], ql[nf][ks], acc[nf]);
      }
    }
    // wave-level row-chunk max (reduce over q groups)
    float wmax[2];
    #pragma unroll
    for (int nf = 0; nf < 2; nf++) {
      float v = fmaxf(fmaxf(acc[nf][0], acc[nf][1]), fmaxf(acc[nf][2], acc[nf][3]));
      v = fmaxf(v, __shfl_xor(v, 16));
      v = fmaxf(v, __shfl_xor(v, 32));
      wmax[nf] = v;
    }
    if (q == 0) { redm[c&1][wave][r] = wmax[0]; redm[c&1][wave][16+r] = wmax[1]; }
    __syncthreads();                       // 1 barrier/chunk
    #pragma unroll
    for (int nf = 0; nf < 2; nf++) {
      int row = nf*16 + r;
      float mc = redm[c&1][0][row];
      #pragma unroll
      for (int w2 = 1; w2 < 8; w2++) mc = fmaxf(mc, redm[c&1][w2][row]);
      float mnew = fmaxf(m_run[nf], mc);
      unsigned s0 = (unsigned)(__expf(acc[nf][0]-mnew)*65535.f + 0.5f);
      unsigned s1 = (unsigned)(__expf(acc[nf][1]-mnew)*65535.f + 0.5f);
      unsigned s2 = (unsigned)(__expf(acc[nf][2]-mnew)*65535.f + 0.5f);
      unsigned s3 = (unsigned)(__expf(acc[nf][3]-mnew)*65535.f + 0.5f);
      *(uint2*)(P + pbase + (size_t)row*SEQ + c*128 + mb + q*4) =
          make_uint2(s0 | (s1 << 16), s2 | (s3 << 16));
      s_run[nf] = s_run[nf]*__expf(m_run[nf]-mnew) + (float)(s0+s1+s2+s3);
      m_run[nf] = mnew;
      if (wave == 0 && q == 0) musd[row][c] = mnew;
    }
  }

  // ---- final sum reduction + F table
  #pragma unroll
  for (int nf = 0; nf < 2; nf++) {
    float s = s_run[nf];
    s += __shfl_xor(s, 16);
    s += __shfl_xor(s, 32);
    if (q == 0) reds[wave][nf*16 + r] = s;
  }
  __syncthreads();
  if (tid < 32) {
    int row = tid;
    float S = 0.f;
    #pragma unroll
    for (int w2 = 0; w2 < 8; w2++) S += reds[w2][row];
    float mfin = musd[row][7];
    float inv = 1.0f / S;
    size_t fb = ((size_t)(b*NH + h)*SEQ + n0 + row)*8;
    #pragma unroll
    for (int c = 0; c < 8; c++)
      F[fb + c] = __expf(musd[row][c] - mfin) * inv;
  }
}

// ---------------------------------------------------------------------------
// K_attn: dequant-transpose P[b][h][n][m] u16 * F -> attn[b][n][m][h] f32.
// One thread per (b,n,m): 16 coalesced u16 loads + 16 L2-hot F loads,
// 4 contiguous float4 stores.
// ---------------------------------------------------------------------------
__global__ __launch_bounds__(256) void k_attn_write(
    const unsigned short* __restrict__ P, const float* __restrict__ F,
    float* __restrict__ attn)
{
  int T = blockIdx.x*256 + threadIdx.x;
  int b = T >> 20, rem = T & 1048575;
  int n = rem >> 10, m = rem & 1023;
  int c = m >> 7;
  const size_t pb = ((size_t)(b*NH)*SEQ + n)*SEQ + m;
  const size_t fb = ((size_t)(b*NH)*SEQ + n)*8 + c;
  float v[16];
  #pragma unroll
  for (int h = 0; h < 16; h++)
    v[h] = (float)P[pb + (size_t)h*SEQ*SEQ] * F[fb + (size_t)h*SEQ*8];
  size_t ob = ((size_t)(b*SEQ + n)*SEQ + m)*16;
  #pragma unroll
  for (int g = 0; g < 4; g++)
    *(float4*)(attn + ob + g*4) = make_float4(v[g*4], v[g*4+1], v[g*4+2], v[g*4+3]);
}

// ---------------------------------------------------------------------------
// K4: PV gemm per (b,h):  OA[n][d] = sum_c F[n][c] * sum_{m in c} P_u16 * V
// 64n x 64d per block (512 blocks); exact byte-split planes of stored u16;
// per-chunk fold accF += acc * F.  Same group-XOR LDS swizzle as gemm_core.
// ---------------------------------------------------------------------------
__global__ __launch_bounds__(256) void k_pv(
    const unsigned short* __restrict__ P, const float* __restrict__ F,
    const unsigned short* __restrict__ Vthi, const unsigned short* __restrict__ Vtlo,
    unsigned short* __restrict__ OAhi, unsigned short* __restrict__ OAlo)
{
  int nt = blockIdx.x, h = blockIdx.y, b = blockIdx.z;
  int n0 = nt * 64;
  __shared__ unsigned short sPa[64*32], sPb[64*32], sVh[64*32], sVl[64*32];
  const int tid = threadIdx.x, lane = tid & 63, wave = tid >> 6;
  const int wm = wave & 1, wn = wave >> 1;
  const int r = lane & 15, q = lane >> 4;
  const int crow = lane >> 2;
  const int cgsw = ((lane & 3) ^ ((crow >> 1) & 3)) * 8;   // swizzled src group
  const int qsw = (q ^ ((r >> 1) & 3)) * 8;                // swizzled read group
  const size_t pbase = ((size_t)(b*NH + h))*SEQ*SEQ;
  const size_t vbase = ((size_t)(b*NH + h))*HD*SEQ;
  const size_t fbase = ((size_t)(b*NH + h))*SEQ*8;

  f32x4 acc[2][2], accF[2][2];
  #pragma unroll
  for (int i = 0; i < 2; i++)
    #pragma unroll
    for (int j = 0; j < 2; j++) {
      acc[i][j][0]=0.f; acc[i][j][1]=0.f; acc[i][j][2]=0.f; acc[i][j][3]=0.f;
      accF[i][j][0]=0.f; accF[i][j][1]=0.f; accF[i][j][2]=0.f; accF[i][j][3]=0.f;
    }

  for (int k0 = 0; k0 < SEQ; k0 += 32) {
    #pragma unroll
    for (int t = 0; t < 2; t++) {
      int c = wave + t*4;
      const unsigned short* gb = (c < 4) ? Vthi : Vtlo;
      unsigned short* sb = (c < 4) ? (unsigned short*)sVh : (unsigned short*)sVl;
      int rr = c & 3;
      int row = rr*16 + crow;
      gl_lds16(gb + vbase + (size_t)row*SEQ + k0 + cgsw, sb + rr*512);
    }
    {
      int row = tid >> 2, g = tid & 3, ch = g * 8;
      int gp = (g ^ ((row >> 1) & 3)) * 8;                 // swizzled LDS slot
      uint4 v = *(const uint4*)(P + pbase + (size_t)(n0 + row)*SEQ + k0 + ch);
      unsigned int wds[4] = {v.x, v.y, v.z, v.w};
      unsigned int pa[4], pb4[4];
      #pragma unroll
      for (int e = 0; e < 4; e++) {
        unsigned int lo16 = wds[e] & 0xFFFFu;
        unsigned int hi16 = wds[e] >> 16;
        unsigned int a0 = __builtin_bit_cast(uint32_t, (float)(lo16 & 0xFF00u)) >> 16;
        unsigned int b0 = __builtin_bit_cast(uint32_t, (float)(lo16 & 0x00FFu)) >> 16;
        unsigned int a1 = __builtin_bit_cast(uint32_t, (float)(hi16 & 0xFF00u)) >> 16;
        unsigned int b1 = __builtin_bit_cast(uint32_t, (float)(hi16 & 0x00FFu)) >> 16;
        pa[e]  = a0 | (a1 << 16);
        pb4[e] = b0 | (b1 << 16);
      }
      *(uint4*)(sPa + row*32 + gp) = make_uint4(pa[0],pa[1],pa[2],pa[3]);
      *(uint4*)(sPb + row*32 + gp) = make_uint4(pb4[0],pb4[1],pb4[2],pb4[3]);
    }
    __syncthreads();
    bf16x8 pa[2], pb2[2], vh[2], vl[2];
    #pragma unroll
    for (int i = 0; i < 2; i++) {
      int off = (wm*32 + i*16 + r)*32 + qsw;
      pa[i]  = *(const bf16x8*)(sPa + off);
      pb2[i] = *(const bf16x8*)(sPb + off);
    }
    #pragma unroll
    for (int j = 0; j < 2; j++) {
      int off = (wn*32 + j*16 + r)*32 + qsw;
      vh[j] = *(const bf16x8*)(sVh + off);
      vl[j] = *(const bf16x8*)(sVl + off);
    }
    #pragma unroll
    for (int i = 0; i < 2; i++)
      #pragma unroll
      for (int j = 0; j < 2; j++) {
        acc[i][j] = MFMA16(pa[i],  vh[j], acc[i][j]);
        acc[i][j] = MFMA16(pb2[i], vh[j], acc[i][j]);
        acc[i][j] = MFMA16(pa[i],  vl[j], acc[i][j]);
      }
    if ((k0 & 127) == 96) {                // end of 128-m chunk: fold with F
      int c = k0 >> 7;
      #pragma unroll
      for (int i = 0; i < 2; i++)
        #pragma unroll
        for (int t = 0; t < 4; t++) {
          int nn = n0 + wm*32 + i*16 + q*4 + t;
          float Fv = F[fbase + (size_t)nn*8 + c];
          #pragma unroll
          for (int j = 0; j < 2; j++) {
            accF[i][j][t] += acc[i][j][t] * Fv;
            acc[i][j][t] = 0.f;
          }
        }
    }
    __syncthreads();
  }
  #pragma unroll
  for (int i = 0; i < 2; i++)
    #pragma unroll
    for (int t = 0; t < 4; t++) {
      int nn = n0 + wm*32 + i*16 + q*4 + t;
      #pragma unroll
      for (int j = 0; j < 2; j++) {
        int d = wn*32 + j*16 + r;
        float val = accF[i][j][t];
        size_t o = (size_t)(b*SEQ + nn)*CDIM + h*HD + d;
        unsigned short hb = f2bf(val);
        OAhi[o] = hb; OAlo[o] = f2bf(val - bf2f(hb));
      }
    }
}

// ---------------------------------------------------------------------------
extern "C" void kernel_launch(void* const* d_in, const int* in_sizes, int n_in,
                              void* d_out, int out_size, void* d_ws, size_t ws_size,
                              hipStream_t stream)
{
  const float* x   = (const float*)d_in[0];
  const float* Wq  = (const float*)d_in[1];
  const float* bq  = (const float*)d_in[2];
  const float* Wkv = (const float*)d_in[3];
  const float* bkv = (const float*)d_in[4];
  const float* Wp  = (const float*)d_in[5];
  const float* bp  = (const float*)d_in[6];

  float* out  = (float*)d_out;
  float* attn = out + (size_t)ROWS*CDIM;

  char* w = (char*)d_ws;
  unsigned short* Xhi  = (unsigned short*)w; w += (size_t)ROWS*CDIM*2;
  unsigned short* Xlo  = (unsigned short*)w; w += (size_t)ROWS*CDIM*2;
  unsigned short* Whi  = (unsigned short*)w; w += (size_t)4096*CDIM*2;
  unsigned short* Wlo  = (unsigned short*)w; w += (size_t)4096*CDIM*2;
  unsigned short* Qhi  = (unsigned short*)w; w += (size_t)ROWS*CDIM*2;
  unsigned short* Qlo  = (unsigned short*)w; w += (size_t)ROWS*CDIM*2;
  unsigned short* Khi  = (unsigned short*)w; w += (size_t)ROWS*CDIM*2;
  unsigned short* Klo  = (unsigned short*)w; w += (size_t)ROWS*CDIM*2;
  unsigned short* Vthi = (unsigned short*)w; w += (size_t)NB*NH*HD*SEQ*2;
  unsigned short* Vtlo = (unsigned short*)w; w += (size_t)NB*NH*HD*SEQ*2;
  unsigned short* OAhi = (unsigned short*)w; w += (size_t)ROWS*CDIM*2;
  unsigned short* OAlo = (unsigned short*)w; w += (size_t)ROWS*CDIM*2;
  unsigned short* P    = (unsigned short*)w; w += (size_t)NB*NH*SEQ*SEQ*2;
  float*          Ftab = (float*)w;          w += (size_t)NB*NH*SEQ*8*4;

  k_convert<<<dim3((ROWS*CDIM + 4096*CDIM)/256), 256, 0, stream>>>(
      x, Wq, Wkv, Wp, Xhi, Xlo, Whi, Wlo);

  k_gemm_qkv<<<dim3(3072/64, 2048/128), 256, 0, stream>>>(
      Xhi, Xlo, Whi, Wlo, bq, bkv, Qhi, Qlo, Khi, Klo, Vthi, Vtlo);

  k_logits_softmax<<<dim3(SEQ/32, NH, NB), 512, 0, stream>>>(
      Qhi, Qlo, Khi, Klo, P, Ftab);

  k_pv<<<dim3(SEQ/64, NH, NB), 256, 0, stream>>>(P, Ftab, Vthi, Vtlo, OAhi, OAlo);

  k_gemm_out<<<dim3(1024/64, 2048/128), 512, 0, stream>>>(
      OAhi, OAlo, Whi + (size_t)3072*CDIM, Wlo + (size_t)3072*CDIM, bp, out);

  k_attn_write<<<dim3((NB*SEQ*SEQ)/256), 256, 0, stream>>>(P, Ftab, attn);
}